// Round 15
// baseline (261.797 us; speedup 1.0000x reference)
//
#include <hip/hip_runtime.h>
#include <hip/hip_fp16.h>
#include <math.h>

#define NN 100000
#define EE 1600000
#define GG 64
#define HH 64
#define LHH 128
#define AA 10

#define NBUCK 391            // ceil(NN/256): 256 dst nodes per bucket
#define EPB 8192             // edges per chunk
#define NCHUNK 196           // ceil(EE/EPB)
#define SCAN_T (NBUCK * NCHUNK)               // 76636
#define SCAN_NB ((SCAN_T + 1023) / 1024)      // 75
#define FCAP 8192            // LDS staging capacity in csr_fine (max bucket ~4500)
#define MM_NPB 16            // nodes per block in mm (4 waves x 4 nodes)

// ---------------- helpers ----------------
__device__ __forceinline__ float wave_sum(float v) {
#pragma unroll
    for (int m = 32; m >= 1; m >>= 1) v += __shfl_xor(v, m, 64);
    return v;
}
__device__ __forceinline__ float sigmoidf(float x) { return 1.f / (1.f + expf(-x)); }

// ---------------- fused encoder + mm1: h = LN(relu(x@enc_w+enc_b));
// hw = h@W -> fp16 Xh; as/ad dots. h never touches global memory. ----------
__global__ __launch_bounds__(256) void encmm_kernel(
    const float* __restrict__ x, const float* __restrict__ enc_w,
    const float* __restrict__ enc_b, const float* __restrict__ ln_g,
    const float* __restrict__ ln_b,
    const float* __restrict__ W, const float* __restrict__ avs,
    const float* __restrict__ avd, __half* __restrict__ Xh,
    float* __restrict__ as_out, float* __restrict__ ad_out) {
    __shared__ float4 sW4[64 * 16];     // 16 KB
    __shared__ float srow[MM_NPB][68];  // 64 cols + 4 pad
    __shared__ float sw[5 * 64];
    int t = threadIdx.x;
    const float4* __restrict__ W4 = (const float4*)W;
#pragma unroll
    for (int i = t; i < 1024; i += 256) sW4[i] = W4[i];
    for (int i = t; i < 320; i += 256) sw[i] = enc_w[i];
    __syncthreads();
    int wave = t >> 6, lane = t & 63;
    int vbase = blockIdx.x * MM_NPB;
    float eb = enc_b[lane], lg = ln_g[lane], lb = ln_b[lane];
    // encoder: each wave computes its 4 nodes into srow
#pragma unroll
    for (int p = 0; p < 4; ++p) {
        int vl = wave * 4 + p;
        int v = vbase + vl;
        if (v < NN) {
            float a = eb;
#pragma unroll
            for (int k = 0; k < 5; ++k) a += x[v * 5 + k] * sw[k * 64 + lane];
            a = fmaxf(a, 0.f);
            float mu = wave_sum(a) * (1.f / 64.f);
            float d = a - mu;
            float var = wave_sum(d * d) * (1.f / 64.f);
            float r = 1.f / sqrtf(var + 1e-5f);
            srow[vl][lane] = d * r * lg + lb;
        }
    }
    __syncthreads();
    // mm: wave handles 4 nodes; lane = (grp: node, sl: 4-col float4)
    int grp = lane >> 4, sl = lane & 15;
    int vl = wave * 4 + grp;
    int v = vbase + vl;
    if (v >= NN) return;
    float4 acc = make_float4(0.f, 0.f, 0.f, 0.f);
#pragma unroll
    for (int k4 = 0; k4 < 16; ++k4) {
        float4 h4 = *(const float4*)&srow[vl][k4 * 4];
        float4 w0 = sW4[(k4 * 4 + 0) * 16 + sl];
        float4 w1 = sW4[(k4 * 4 + 1) * 16 + sl];
        float4 w2 = sW4[(k4 * 4 + 2) * 16 + sl];
        float4 w3 = sW4[(k4 * 4 + 3) * 16 + sl];
        acc.x = fmaf(h4.x, w0.x, acc.x);
        acc.y = fmaf(h4.x, w0.y, acc.y);
        acc.z = fmaf(h4.x, w0.z, acc.z);
        acc.w = fmaf(h4.x, w0.w, acc.w);
        acc.x = fmaf(h4.y, w1.x, acc.x);
        acc.y = fmaf(h4.y, w1.y, acc.y);
        acc.z = fmaf(h4.y, w1.z, acc.z);
        acc.w = fmaf(h4.y, w1.w, acc.w);
        acc.x = fmaf(h4.z, w2.x, acc.x);
        acc.y = fmaf(h4.z, w2.y, acc.y);
        acc.z = fmaf(h4.z, w2.z, acc.z);
        acc.w = fmaf(h4.z, w2.w, acc.w);
        acc.x = fmaf(h4.w, w3.x, acc.x);
        acc.y = fmaf(h4.w, w3.y, acc.y);
        acc.z = fmaf(h4.w, w3.z, acc.z);
        acc.w = fmaf(h4.w, w3.w, acc.w);
    }
    float4 s4 = ((const float4*)avs)[sl];
    float4 d4 = ((const float4*)avd)[sl];
    float pa = acc.x * s4.x + acc.y * s4.y + acc.z * s4.z + acc.w * s4.w;
    float pd = acc.x * d4.x + acc.y * d4.y + acc.z * d4.z + acc.w * d4.w;
#pragma unroll
    for (int m = 1; m <= 8; m <<= 1) {
        pa += __shfl_xor(pa, m, 64);
        pd += __shfl_xor(pd, m, 64);
    }
    if (sl == 0) { as_out[v] = pa; ad_out[v] = pd; }
    __half2 lo = __floats2half2_rn(acc.x, acc.y);
    __half2 hi = __floats2half2_rn(acc.z, acc.w);
    uint2 pk;
    pk.x = *(unsigned int*)&lo;
    pk.y = *(unsigned int*)&hi;
    ((uint2*)Xh)[(size_t)v * 16 + sl] = pk;
}

// ---------------- mm (layer 2): hw = buf@W -> fp16 Xh; as/ad dots -----------
__global__ __launch_bounds__(256) void mm_kernel(
    const float* __restrict__ buf, const float* __restrict__ W,
    const float* __restrict__ avs, const float* __restrict__ avd,
    __half* __restrict__ Xh,
    float* __restrict__ as_out, float* __restrict__ ad_out) {
    __shared__ float4 sW4[64 * 16];       // W row-major as float4 col-quads
    __shared__ float4 srow4[MM_NPB][17];  // +1 pad
    int t = threadIdx.x;
    const float4* __restrict__ W4 = (const float4*)W;
    const float4* __restrict__ buf4 = (const float4*)buf;
#pragma unroll
    for (int i = t; i < 1024; i += 256) sW4[i] = W4[i];
    int vbase = blockIdx.x * MM_NPB;
    {
        int vl = t >> 4, c = t & 15;
        int v = vbase + vl;
        if (v < NN) srow4[vl][c] = buf4[(size_t)v * 16 + c];
    }
    __syncthreads();
    int wave = t >> 6, lane = t & 63;
    int grp = lane >> 4, sl = lane & 15;
    int vl = wave * 4 + grp;
    int v = vbase + vl;
    if (v >= NN) return;
    float4 acc = make_float4(0.f, 0.f, 0.f, 0.f);
#pragma unroll
    for (int k4 = 0; k4 < 16; ++k4) {
        float4 h4 = srow4[vl][k4];
        float4 w0 = sW4[(k4 * 4 + 0) * 16 + sl];
        float4 w1 = sW4[(k4 * 4 + 1) * 16 + sl];
        float4 w2 = sW4[(k4 * 4 + 2) * 16 + sl];
        float4 w3 = sW4[(k4 * 4 + 3) * 16 + sl];
        acc.x = fmaf(h4.x, w0.x, acc.x);
        acc.y = fmaf(h4.x, w0.y, acc.y);
        acc.z = fmaf(h4.x, w0.z, acc.z);
        acc.w = fmaf(h4.x, w0.w, acc.w);
        acc.x = fmaf(h4.y, w1.x, acc.x);
        acc.y = fmaf(h4.y, w1.y, acc.y);
        acc.z = fmaf(h4.y, w1.z, acc.z);
        acc.w = fmaf(h4.y, w1.w, acc.w);
        acc.x = fmaf(h4.z, w2.x, acc.x);
        acc.y = fmaf(h4.z, w2.y, acc.y);
        acc.z = fmaf(h4.z, w2.z, acc.z);
        acc.w = fmaf(h4.z, w2.w, acc.w);
        acc.x = fmaf(h4.w, w3.x, acc.x);
        acc.y = fmaf(h4.w, w3.y, acc.y);
        acc.z = fmaf(h4.w, w3.z, acc.z);
        acc.w = fmaf(h4.w, w3.w, acc.w);
    }
    float4 s4 = ((const float4*)avs)[sl];
    float4 d4 = ((const float4*)avd)[sl];
    float pa = acc.x * s4.x + acc.y * s4.y + acc.z * s4.z + acc.w * s4.w;
    float pd = acc.x * d4.x + acc.y * d4.y + acc.z * d4.z + acc.w * d4.w;
#pragma unroll
    for (int m = 1; m <= 8; m <<= 1) {
        pa += __shfl_xor(pa, m, 64);
        pd += __shfl_xor(pd, m, 64);
    }
    if (sl == 0) { as_out[v] = pa; ad_out[v] = pd; }
    __half2 lo = __floats2half2_rn(acc.x, acc.y);
    __half2 hi = __floats2half2_rn(acc.z, acc.w);
    uint2 pk;
    pk.x = *(unsigned int*)&lo;
    pk.y = *(unsigned int*)&hi;
    ((uint2*)Xh)[(size_t)v * 16 + sl] = pk;
}

// ---------------- CSR build: bucket sort (LDS atomics only) ----------------
__global__ __launch_bounds__(256) void bucket_count_kernel(const int* __restrict__ dst,
                                                           int* __restrict__ cntAC) {
    __shared__ int lcnt[NBUCK];
    int c = blockIdx.x, t = threadIdx.x;
    for (int j = t; j < NBUCK; j += 256) lcnt[j] = 0;
    __syncthreads();
    int beg = c * EPB, end = beg + EPB;
    if (end > EE) end = EE;
    for (int i = beg + t; i < end; i += 256) atomicAdd(&lcnt[dst[i] >> 8], 1);
    __syncthreads();
    for (int j = t; j < NBUCK; j += 256) cntAC[j * NCHUNK + c] = lcnt[j];
}

__global__ __launch_bounds__(256) void scanA_kernel(int* __restrict__ cntAC,
                                                    int* __restrict__ bsum) {
    __shared__ int sd[256];
    int t = threadIdx.x, b = blockIdx.x;
    int base = b * 1024 + t * 4;
    int v0 = (base + 0 < SCAN_T) ? cntAC[base + 0] : 0;
    int v1 = (base + 1 < SCAN_T) ? cntAC[base + 1] : 0;
    int v2 = (base + 2 < SCAN_T) ? cntAC[base + 2] : 0;
    int v3 = (base + 3 < SCAN_T) ? cntAC[base + 3] : 0;
    int tot = v0 + v1 + v2 + v3;
    sd[t] = tot;
    __syncthreads();
    for (int off = 1; off < 256; off <<= 1) {
        int xx = (t >= off) ? sd[t - off] : 0;
        __syncthreads();
        sd[t] += xx;
        __syncthreads();
    }
    int p = sd[t] - tot;  // exclusive within block
    if (t == 255) bsum[b] = sd[255];
    if (base + 0 < SCAN_T) cntAC[base + 0] = p; p += v0;
    if (base + 1 < SCAN_T) cntAC[base + 1] = p; p += v1;
    if (base + 2 < SCAN_T) cntAC[base + 2] = p; p += v2;
    if (base + 3 < SCAN_T) cntAC[base + 3] = p;
}

__global__ __launch_bounds__(256) void scanB_kernel(int* __restrict__ bsum, int nb) {
    __shared__ int sd[256];
    int t = threadIdx.x;
    int v = (t < nb) ? bsum[t] : 0;
    sd[t] = v;
    __syncthreads();
    for (int off = 1; off < 256; off <<= 1) {
        int xx = (t >= off) ? sd[t - off] : 0;
        __syncthreads();
        sd[t] += xx;
        __syncthreads();
    }
    if (t < nb) bsum[t] = sd[t] - v;  // exclusive
}

__global__ __launch_bounds__(256) void scanC_kernel(int* __restrict__ cntAC,
                                                    const int* __restrict__ bsum,
                                                    int* __restrict__ row_off,
                                                    int* __restrict__ csr_src) {
    int idx = blockIdx.x * 256 + threadIdx.x;
    if (idx < SCAN_T) cntAC[idx] += bsum[idx >> 10];
    if (idx == 0) row_off[NN] = EE;
    if (idx < 32) csr_src[EE + idx] = 0;  // prefetch slack (valid index 0)
}

__global__ __launch_bounds__(256) void bucket_scatter_kernel(
    const int* __restrict__ src, const int* __restrict__ dst,
    const int* __restrict__ cntAC, int* __restrict__ eed) {
    __shared__ int lcur[NBUCK];
    int c = blockIdx.x, t = threadIdx.x;
    for (int j = t; j < NBUCK; j += 256) lcur[j] = cntAC[j * NCHUNK + c];
    __syncthreads();
    int beg = c * EPB, end = beg + EPB;
    if (end > EE) end = EE;
    for (int i = beg + t; i < end; i += 256) {
        int d = dst[i];
        int s = src[i];
        int pos = atomicAdd(&lcur[d >> 8], 1);
        eed[pos] = (s << 8) | (d & 255);
    }
}

__global__ __launch_bounds__(1024) void csr_fine_kernel(
    const int* __restrict__ eed, const int* __restrict__ cntAC,
    int* __restrict__ row_off, int* __restrict__ csr_src) {
    int b = blockIdx.x, t = threadIdx.x;
    int bb = cntAC[b * NCHUNK];
    int be = (b + 1 < NBUCK) ? cntAC[(b + 1) * NCHUNK] : EE;
    __shared__ int lcnt[256], lscan[256], lcur[256];
    __shared__ int stage[FCAP];
    if (t < 256) lcnt[t] = 0;
    __syncthreads();
    for (int i = bb + t; i < be; i += 1024) {
        int w = eed[i];
        int off = i - bb;
        if (off < FCAP) stage[off] = w;
        atomicAdd(&lcnt[w & 255], 1);
    }
    __syncthreads();
    if (t < 256) lscan[t] = lcnt[t];
    __syncthreads();
    for (int off = 1; off < 256; off <<= 1) {
        int xx = 0;
        if (t < 256 && t >= off) xx = lscan[t - off];
        __syncthreads();
        if (t < 256) lscan[t] += xx;
        __syncthreads();
    }
    if (t < 256) {
        int excl = lscan[t] - lcnt[t];
        lcur[t] = excl;
        int node = (b << 8) + t;
        if (node < NN) row_off[node] = bb + excl;
    }
    __syncthreads();
    for (int i = bb + t; i < be; i += 1024) {
        int off = i - bb;
        int w = (off < FCAP) ? stage[off] : eed[i];
        int pos = bb + atomicAdd(&lcur[w & 255], 1);
        csr_src[pos] = w >> 8;
    }
}

// ---------------- GAT: wave per dst node, 8 edges/iter, 8-lane groups each
// covering 8 cols via one fp16x8 (uint4) gather. fp32 accumulate. Explicit
// 1-stage pipeline (depth-2 on indices, depth-1 on data) — load-bearing:
// hipcc does NOT hoist gathers across iterations (r12 regression 60->68us).
// unroll 2 deletes rotation movs. Index loads unguarded (csr has 32 slack
// entries); only ex is predicated — dead slots contribute exactly 0. -------
__global__ __launch_bounds__(256) void gat_kernel(
    const __half* __restrict__ Xh,  // hw fp16 [N][64]
    const float* __restrict__ asn, const float* __restrict__ adn,
    const int* __restrict__ row_off, const int* __restrict__ csr_src,
    const float* __restrict__ bias, float* __restrict__ Y,
    const float* __restrict__ gate_w, const float* __restrict__ gate_b,
    float* __restrict__ gatebuf) {
    int t = threadIdx.x;
    int wave = t >> 6, lane = t & 63;
    int v = blockIdx.x * 4 + wave;
    if (v >= NN) return;
    int grp = lane >> 3, sl = lane & 7;   // 8 groups x 8 lanes
    const uint4* __restrict__ X8 = (const uint4*)Xh;  // 8 halves per uint4
    float adv = adn[v];
    float es = asn[v] + adv;
    es = (es >= 0.f) ? es : 0.2f * es;
    float exs = __expf(es);
    float acc[8];
#pragma unroll
    for (int j = 0; j < 8; ++j) acc[j] = 0.f;
    float den = 0.f;
    if (grp == 0) {  // self loop owned by group 0
        uint4 xw = X8[v * 8 + sl];
        const __half2* hp = (const __half2*)&xw;
#pragma unroll
        for (int j = 0; j < 4; ++j) {
            float2 f = __half22float2(hp[j]);
            acc[2 * j] = exs * f.x;
            acc[2 * j + 1] = exs * f.y;
        }
        den = exs;
    }
    int beg = row_off[v], end = row_off[v + 1];
    // pipeline prologue (unguarded index loads: slack-protected)
    int eA = beg + grp, eB = beg + 8 + grp;
    bool vA = eA < end, vB = eB < end;
    int sA = csr_src[eA];
    int sB = csr_src[eB];
    float asvA = asn[sA];
    uint4 xA = X8[sA * 8 + sl];
#pragma unroll 2
    for (int i = beg; i < end; i += 8) {
        // prefetch: index for i+16, data for i+8
        int eC = i + 16 + grp;
        bool vC = eC < end;
        int sC = csr_src[eC];
        float asvB = asn[sB];
        uint4 xB = X8[sB * 8 + sl];
        // compute on A (landed a full iteration ago)
        float ee = asvA + adv;
        ee = (ee >= 0.f) ? ee : 0.2f * ee;
        float ex = vA ? __expf(ee) : 0.f;
        const __half2* hp = (const __half2*)&xA;
#pragma unroll
        for (int j = 0; j < 4; ++j) {
            float2 f = __half22float2(hp[j]);
            acc[2 * j] = fmaf(ex, f.x, acc[2 * j]);
            acc[2 * j + 1] = fmaf(ex, f.y, acc[2 * j + 1]);
        }
        den += ex;
        // shift
        vA = vB; vB = vC;
        sB = sC;
        asvA = asvB;
        xA = xB;
    }
    // reduce across the 8 lane groups (lanes {sl, sl+8, ..., sl+56})
#pragma unroll
    for (int m = 8; m <= 32; m <<= 1) {
#pragma unroll
        for (int j = 0; j < 8; ++j) acc[j] += __shfl_xor(acc[j], m, 64);
        den += __shfl_xor(den, m, 64);
    }
    float inv = 1.f / (den + 1e-16f);
    float o[8];
#pragma unroll
    for (int j = 0; j < 8; ++j)
        o[j] = fmaxf(acc[j] * inv + bias[sl * 8 + j], 0.f);
    if (grp == 0) {
        float4 o0 = make_float4(o[0], o[1], o[2], o[3]);
        float4 o1 = make_float4(o[4], o[5], o[6], o[7]);
        ((float4*)Y)[v * 16 + sl * 2] = o0;
        ((float4*)Y)[v * 16 + sl * 2 + 1] = o1;
    }
    if (gatebuf) {  // fused pool gate (layer 2 only)
        float p = 0.f;
#pragma unroll
        for (int j = 0; j < 8; ++j) p = fmaf(o[j], gate_w[sl * 8 + j], p);
        float gate = wave_sum(p) * 0.125f + gate_b[0];  // each col counted 8x
        if (lane == 0) gatebuf[v] = gate;
    }
}

// ---------------- pool: contiguous strip per wave, register accumulation,
// flush on graph change (batch sorted). NPW=16 for 2x block parallelism;
// explicit next-node prefetch (compiler won't hoist past the flush branch). -
#define POOL_NPW 16  // nodes per wave
__global__ __launch_bounds__(256) void pool_kernel(
    const float* __restrict__ Hf, const float* __restrict__ gatebuf,
    const int* __restrict__ batch,
    float* __restrict__ acc, float* __restrict__ den) {
    int t = threadIdx.x, wave = t >> 6, lane = t & 63;
    int v0 = (blockIdx.x * 4 + wave) * POOL_NPW;
    if (v0 >= NN) return;
    int vend = v0 + POOL_NPW;
    if (vend > NN) vend = NN;
    int gcur = batch[v0];
    float accr = 0.f, denr = 0.f;
    // prefetch node v0
    int gN = gcur;
    float gateN = gatebuf[v0];
    float hN = Hf[(size_t)v0 * 64 + lane];
    for (int v = v0; v < vend; ++v) {
        int gC = gN;
        float gateC = gateN;
        float hC = hN;
        if (v + 1 < vend) {  // prefetch next node before branch+compute
            gN = batch[v + 1];
            gateN = gatebuf[v + 1];
            hN = Hf[(size_t)(v + 1) * 64 + lane];
        }
        if (gC != gcur) {  // wave-uniform flush
            atomicAdd(&acc[gcur * 64 + lane], accr);
            if (lane == 0) atomicAdd(&den[gcur], denr);
            accr = 0.f; denr = 0.f; gcur = gC;
        }
        float ex = __expf(gateC);
        accr = fmaf(ex, hC, accr);
        denr += ex;
    }
    atomicAdd(&acc[gcur * 64 + lane], accr);
    if (lane == 0) atomicAdd(&den[gcur], denr);
}

// ---------------- pool finalize + LSTM (h0=c0=0) + MLP head ----------------
__global__ __launch_bounds__(256) void head_kernel(
    const float* __restrict__ acc, const float* __restrict__ den,
    const float* __restrict__ w_ih,
    const float* __restrict__ b_ih, const float* __restrict__ b_hh,
    const float* __restrict__ q_w1, const float* __restrict__ q_b1,
    const float* __restrict__ q_w2, const float* __restrict__ q_b2,
    float* __restrict__ out) {
    int g = blockIdx.x, t = threadIdx.x;
    __shared__ float sp[64];
    __shared__ float sg[512];
    __shared__ float sh1[128];
    __shared__ float ss1[64];
    if (t < 64) sp[t] = acc[g * 64 + t] / (den[g] + 1e-16f);
    __syncthreads();
    for (int r = t; r < 512; r += 256) {
        const float* wr = w_ih + (size_t)r * 64;
        float a = b_ih[r] + b_hh[r];
#pragma unroll
        for (int k = 0; k < 64; ++k) a += sp[k] * wr[k];
        sg[r] = a;
    }
    __syncthreads();
    if (t < 128) {
        float ig = sg[t], gg = sg[256 + t], og = sg[384 + t];
        float c1 = sigmoidf(ig) * tanhf(gg);  // sigmoid(f)*c0 == 0
        float h1 = sigmoidf(og) * tanhf(c1);
        sh1[t] = h1;
        out[640 + g * 128 + t] = h1;
        out[640 + 8192 + g * 128 + t] = c1;
    }
    __syncthreads();
    if (t < 64) {
        float a = q_b1[t];
#pragma unroll
        for (int k = 0; k < 128; ++k) a += sh1[k] * q_w1[k * 64 + t];
        ss1[t] = fmaxf(a, 0.f);
    }
    __syncthreads();
    if (t < 10) {
        float a = q_b2[t];
#pragma unroll
        for (int k = 0; k < 64; ++k) a += ss1[k] * q_w2[k * 10 + t];
        out[g * 10 + t] = a;
    }
}

// ---------------- launcher ----------------
extern "C" void kernel_launch(void* const* d_in, const int* in_sizes, int n_in,
                              void* d_out, int out_size, void* d_ws, size_t ws_size,
                              hipStream_t stream) {
    const float* x = (const float*)d_in[0];
    const int* edge_index = (const int*)d_in[1];
    const int* batch = (const int*)d_in[2];
    const float* enc_w = (const float*)d_in[3];
    const float* enc_b = (const float*)d_in[4];
    const float* ln_g = (const float*)d_in[5];
    const float* ln_b = (const float*)d_in[6];
    const float* w1 = (const float*)d_in[7];
    const float* a1s = (const float*)d_in[8];
    const float* a1d = (const float*)d_in[9];
    const float* b1 = (const float*)d_in[10];
    const float* w2 = (const float*)d_in[11];
    const float* a2s = (const float*)d_in[12];
    const float* a2d = (const float*)d_in[13];
    const float* b2 = (const float*)d_in[14];
    const float* gate_w = (const float*)d_in[15];
    const float* gate_b = (const float*)d_in[16];
    const float* w_ih = (const float*)d_in[17];
    // d_in[18] = w_hh unused (h0 = 0)
    const float* b_ih = (const float*)d_in[19];
    const float* b_hh = (const float*)d_in[20];
    const float* q_w1 = (const float*)d_in[21];
    const float* q_b1 = (const float*)d_in[22];
    const float* q_w2 = (const float*)d_in[23];
    const float* q_b2 = (const float*)d_in[24];
    float* out = (float*)d_out;

    const int* e_src = edge_index;
    const int* e_dst = edge_index + EE;

    // workspace carve-up
    char* ws = (char*)d_ws;
    size_t off = 0;
    auto alloc = [&](size_t bytes) {
        size_t r = off;
        off = (off + bytes + 255) & ~(size_t)255;
        return r;
    };
    float* bufA = (float*)(ws + alloc((size_t)NN * 64 * 4));
    float* bufB = (float*)(ws + alloc((size_t)NN * 64 * 4));
    __half* Xh = (__half*)(ws + alloc((size_t)NN * 64 * 2));
    float* as_n = (float*)(ws + alloc((size_t)NN * 4));
    float* ad_n = (float*)(ws + alloc((size_t)NN * 4));
    float* gatebuf = (float*)(ws + alloc((size_t)NN * 4));
    int* row_off = (int*)(ws + alloc((size_t)(NN + 1) * 4));
    int* csr_src = (int*)(ws + alloc((size_t)(EE + 32) * 4));
    int* cntAC = (int*)(ws + alloc((size_t)SCAN_T * 4));
    int* bsum = (int*)(ws + alloc((size_t)SCAN_NB * 4));
    float* pacc = (float*)(ws + alloc((size_t)GG * 64 * 4));
    float* pden = (float*)(ws + alloc((size_t)GG * 4));
    // packed edge array aliases bufB (dead before gat layer 1 writes bufB)
    int* eed = (int*)bufB;
    (void)ws_size;

    const int nodeBlocks = (NN + 3) / 4;  // wave per node
    const int mmBlocks = (NN + MM_NPB - 1) / MM_NPB;
    const int poolBlocks = (NN + 4 * POOL_NPW - 1) / (4 * POOL_NPW);
    const int scanCBlocks = (SCAN_T + 255) / 256;

    // CSR by dst via bucket sort (LDS atomics only; reused by both GAT layers)
    bucket_count_kernel<<<NCHUNK, 256, 0, stream>>>(e_dst, cntAC);
    scanA_kernel<<<SCAN_NB, 256, 0, stream>>>(cntAC, bsum);
    scanB_kernel<<<1, 256, 0, stream>>>(bsum, SCAN_NB);
    scanC_kernel<<<scanCBlocks, 256, 0, stream>>>(cntAC, bsum, row_off, csr_src);
    bucket_scatter_kernel<<<NCHUNK, 256, 0, stream>>>(e_src, e_dst, cntAC, eed);
    csr_fine_kernel<<<NBUCK, 1024, 0, stream>>>(eed, cntAC, row_off, csr_src);

    // GAT layer 1: fused enc+mm -> fp16 Xh -> gat -> bufB(h1)
    encmm_kernel<<<mmBlocks, 256, 0, stream>>>(x, enc_w, enc_b, ln_g, ln_b,
                                               w1, a1s, a1d, Xh, as_n, ad_n);
    gat_kernel<<<nodeBlocks, 256, 0, stream>>>(Xh, as_n, ad_n, row_off, csr_src,
                                               b1, bufB, nullptr, nullptr, nullptr);

    // GAT layer 2: bufB -> fp16 Xh -> gat -> bufA(h2), fused pool gate
    mm_kernel<<<mmBlocks, 256, 0, stream>>>(bufB, w2, a2s, a2d, Xh, as_n, ad_n);
    gat_kernel<<<nodeBlocks, 256, 0, stream>>>(Xh, as_n, ad_n, row_off, csr_src,
                                               b2, bufA, gate_w, gate_b, gatebuf);

    // pool: register-accumulated partial sums, flush-on-graph-change atomics
    hipMemsetAsync(pacc, 0, (size_t)(GG * 64 + GG) * 4 + 256, stream);
    pool_kernel<<<poolBlocks, 256, 0, stream>>>(bufA, gatebuf, batch, pacc, pden);

    // LSTM + MLP head (pool finalize fused)
    head_kernel<<<GG, 256, 0, stream>>>(pacc, pden, w_ih, b_ih, b_hh,
                                        q_w1, q_b1, q_w2, q_b2, out);
}

// Round 16
// 244.837 us; speedup vs baseline: 1.0693x; 1.0693x over previous
//
#include <hip/hip_runtime.h>
#include <hip/hip_fp16.h>
#include <math.h>

#define NN 100000
#define EE 1600000
#define GG 64
#define HH 64
#define LHH 128
#define AA 10

#define NBUCK 391            // ceil(NN/256): 256 dst nodes per bucket
#define EPB 8192             // edges per chunk (longer scatter runs: ~84B)
#define NCHUNK 196           // ceil(EE/EPB)
#define SCAN_T (NBUCK * NCHUNK)               // 76636
#define SCAN_NB ((SCAN_T + 1023) / 1024)      // 75
#define FCAP 8192            // LDS staging capacity in csr_fine (max bucket ~4500)
#define MM_NPB 16            // nodes per block in mm (4 waves x 4 nodes)

// ---------------- helpers ----------------
__device__ __forceinline__ float wave_sum(float v) {
#pragma unroll
    for (int m = 32; m >= 1; m >>= 1) v += __shfl_xor(v, m, 64);
    return v;
}
__device__ __forceinline__ float sigmoidf(float x) { return 1.f / (1.f + expf(-x)); }

// ---------------- fused encoder + mm1: h = LN(relu(x@enc_w+enc_b));
// hw = h@W -> fp16 Xh; as/ad dots. h never touches global memory. ----------
__global__ __launch_bounds__(256) void encmm_kernel(
    const float* __restrict__ x, const float* __restrict__ enc_w,
    const float* __restrict__ enc_b, const float* __restrict__ ln_g,
    const float* __restrict__ ln_b,
    const float* __restrict__ W, const float* __restrict__ avs,
    const float* __restrict__ avd, __half* __restrict__ Xh,
    float* __restrict__ as_out, float* __restrict__ ad_out) {
    __shared__ float4 sW4[64 * 16];     // 16 KB
    __shared__ float srow[MM_NPB][68];  // 64 cols + 4 pad
    __shared__ float sw[5 * 64];
    int t = threadIdx.x;
    const float4* __restrict__ W4 = (const float4*)W;
#pragma unroll
    for (int i = t; i < 1024; i += 256) sW4[i] = W4[i];
    for (int i = t; i < 320; i += 256) sw[i] = enc_w[i];
    __syncthreads();
    int wave = t >> 6, lane = t & 63;
    int vbase = blockIdx.x * MM_NPB;
    float eb = enc_b[lane], lg = ln_g[lane], lb = ln_b[lane];
    // encoder: each wave computes its 4 nodes into srow
#pragma unroll
    for (int p = 0; p < 4; ++p) {
        int vl = wave * 4 + p;
        int v = vbase + vl;
        if (v < NN) {
            float a = eb;
#pragma unroll
            for (int k = 0; k < 5; ++k) a += x[v * 5 + k] * sw[k * 64 + lane];
            a = fmaxf(a, 0.f);
            float mu = wave_sum(a) * (1.f / 64.f);
            float d = a - mu;
            float var = wave_sum(d * d) * (1.f / 64.f);
            float r = 1.f / sqrtf(var + 1e-5f);
            srow[vl][lane] = d * r * lg + lb;
        }
    }
    __syncthreads();
    // mm: wave handles 4 nodes; lane = (grp: node, sl: 4-col float4)
    int grp = lane >> 4, sl = lane & 15;
    int vl = wave * 4 + grp;
    int v = vbase + vl;
    if (v >= NN) return;
    float4 acc = make_float4(0.f, 0.f, 0.f, 0.f);
#pragma unroll
    for (int k4 = 0; k4 < 16; ++k4) {
        float4 h4 = *(const float4*)&srow[vl][k4 * 4];
        float4 w0 = sW4[(k4 * 4 + 0) * 16 + sl];
        float4 w1 = sW4[(k4 * 4 + 1) * 16 + sl];
        float4 w2 = sW4[(k4 * 4 + 2) * 16 + sl];
        float4 w3 = sW4[(k4 * 4 + 3) * 16 + sl];
        acc.x = fmaf(h4.x, w0.x, acc.x);
        acc.y = fmaf(h4.x, w0.y, acc.y);
        acc.z = fmaf(h4.x, w0.z, acc.z);
        acc.w = fmaf(h4.x, w0.w, acc.w);
        acc.x = fmaf(h4.y, w1.x, acc.x);
        acc.y = fmaf(h4.y, w1.y, acc.y);
        acc.z = fmaf(h4.y, w1.z, acc.z);
        acc.w = fmaf(h4.y, w1.w, acc.w);
        acc.x = fmaf(h4.z, w2.x, acc.x);
        acc.y = fmaf(h4.z, w2.y, acc.y);
        acc.z = fmaf(h4.z, w2.z, acc.z);
        acc.w = fmaf(h4.z, w2.w, acc.w);
        acc.x = fmaf(h4.w, w3.x, acc.x);
        acc.y = fmaf(h4.w, w3.y, acc.y);
        acc.z = fmaf(h4.w, w3.z, acc.z);
        acc.w = fmaf(h4.w, w3.w, acc.w);
    }
    float4 s4 = ((const float4*)avs)[sl];
    float4 d4 = ((const float4*)avd)[sl];
    float pa = acc.x * s4.x + acc.y * s4.y + acc.z * s4.z + acc.w * s4.w;
    float pd = acc.x * d4.x + acc.y * d4.y + acc.z * d4.z + acc.w * d4.w;
#pragma unroll
    for (int m = 1; m <= 8; m <<= 1) {
        pa += __shfl_xor(pa, m, 64);
        pd += __shfl_xor(pd, m, 64);
    }
    if (sl == 0) { as_out[v] = pa; ad_out[v] = pd; }
    __half2 lo = __floats2half2_rn(acc.x, acc.y);
    __half2 hi = __floats2half2_rn(acc.z, acc.w);
    uint2 pk;
    pk.x = *(unsigned int*)&lo;
    pk.y = *(unsigned int*)&hi;
    ((uint2*)Xh)[(size_t)v * 16 + sl] = pk;
}

// ---------------- mm (layer 2): hw = buf@W -> fp16 Xh; as/ad dots -----------
__global__ __launch_bounds__(256) void mm_kernel(
    const float* __restrict__ buf, const float* __restrict__ W,
    const float* __restrict__ avs, const float* __restrict__ avd,
    __half* __restrict__ Xh,
    float* __restrict__ as_out, float* __restrict__ ad_out) {
    __shared__ float4 sW4[64 * 16];       // W row-major as float4 col-quads
    __shared__ float4 srow4[MM_NPB][17];  // +1 pad
    int t = threadIdx.x;
    const float4* __restrict__ W4 = (const float4*)W;
    const float4* __restrict__ buf4 = (const float4*)buf;
#pragma unroll
    for (int i = t; i < 1024; i += 256) sW4[i] = W4[i];
    int vbase = blockIdx.x * MM_NPB;
    {
        int vl = t >> 4, c = t & 15;
        int v = vbase + vl;
        if (v < NN) srow4[vl][c] = buf4[(size_t)v * 16 + c];
    }
    __syncthreads();
    int wave = t >> 6, lane = t & 63;
    int grp = lane >> 4, sl = lane & 15;
    int vl = wave * 4 + grp;
    int v = vbase + vl;
    if (v >= NN) return;
    float4 acc = make_float4(0.f, 0.f, 0.f, 0.f);
#pragma unroll
    for (int k4 = 0; k4 < 16; ++k4) {
        float4 h4 = srow4[vl][k4];
        float4 w0 = sW4[(k4 * 4 + 0) * 16 + sl];
        float4 w1 = sW4[(k4 * 4 + 1) * 16 + sl];
        float4 w2 = sW4[(k4 * 4 + 2) * 16 + sl];
        float4 w3 = sW4[(k4 * 4 + 3) * 16 + sl];
        acc.x = fmaf(h4.x, w0.x, acc.x);
        acc.y = fmaf(h4.x, w0.y, acc.y);
        acc.z = fmaf(h4.x, w0.z, acc.z);
        acc.w = fmaf(h4.x, w0.w, acc.w);
        acc.x = fmaf(h4.y, w1.x, acc.x);
        acc.y = fmaf(h4.y, w1.y, acc.y);
        acc.z = fmaf(h4.y, w1.z, acc.z);
        acc.w = fmaf(h4.y, w1.w, acc.w);
        acc.x = fmaf(h4.z, w2.x, acc.x);
        acc.y = fmaf(h4.z, w2.y, acc.y);
        acc.z = fmaf(h4.z, w2.z, acc.z);
        acc.w = fmaf(h4.z, w2.w, acc.w);
        acc.x = fmaf(h4.w, w3.x, acc.x);
        acc.y = fmaf(h4.w, w3.y, acc.y);
        acc.z = fmaf(h4.w, w3.z, acc.z);
        acc.w = fmaf(h4.w, w3.w, acc.w);
    }
    float4 s4 = ((const float4*)avs)[sl];
    float4 d4 = ((const float4*)avd)[sl];
    float pa = acc.x * s4.x + acc.y * s4.y + acc.z * s4.z + acc.w * s4.w;
    float pd = acc.x * d4.x + acc.y * d4.y + acc.z * d4.z + acc.w * d4.w;
#pragma unroll
    for (int m = 1; m <= 8; m <<= 1) {
        pa += __shfl_xor(pa, m, 64);
        pd += __shfl_xor(pd, m, 64);
    }
    if (sl == 0) { as_out[v] = pa; ad_out[v] = pd; }
    __half2 lo = __floats2half2_rn(acc.x, acc.y);
    __half2 hi = __floats2half2_rn(acc.z, acc.w);
    uint2 pk;
    pk.x = *(unsigned int*)&lo;
    pk.y = *(unsigned int*)&hi;
    ((uint2*)Xh)[(size_t)v * 16 + sl] = pk;
}

// ---------------- CSR build: bucket sort (LDS atomics only) ----------------
__global__ __launch_bounds__(256) void bucket_count_kernel(const int* __restrict__ dst,
                                                           int* __restrict__ cntAC) {
    __shared__ int lcnt[NBUCK];
    int c = blockIdx.x, t = threadIdx.x;
    for (int j = t; j < NBUCK; j += 256) lcnt[j] = 0;
    __syncthreads();
    int beg = c * EPB, end = beg + EPB;
    if (end > EE) end = EE;
    for (int i = beg + t; i < end; i += 256) atomicAdd(&lcnt[dst[i] >> 8], 1);
    __syncthreads();
    for (int j = t; j < NBUCK; j += 256) cntAC[j * NCHUNK + c] = lcnt[j];
}

__global__ __launch_bounds__(256) void scanA_kernel(int* __restrict__ cntAC,
                                                    int* __restrict__ bsum) {
    __shared__ int sd[256];
    int t = threadIdx.x, b = blockIdx.x;
    int base = b * 1024 + t * 4;
    int v0 = (base + 0 < SCAN_T) ? cntAC[base + 0] : 0;
    int v1 = (base + 1 < SCAN_T) ? cntAC[base + 1] : 0;
    int v2 = (base + 2 < SCAN_T) ? cntAC[base + 2] : 0;
    int v3 = (base + 3 < SCAN_T) ? cntAC[base + 3] : 0;
    int tot = v0 + v1 + v2 + v3;
    sd[t] = tot;
    __syncthreads();
    for (int off = 1; off < 256; off <<= 1) {
        int xx = (t >= off) ? sd[t - off] : 0;
        __syncthreads();
        sd[t] += xx;
        __syncthreads();
    }
    int p = sd[t] - tot;  // exclusive within block
    if (t == 255) bsum[b] = sd[255];
    if (base + 0 < SCAN_T) cntAC[base + 0] = p; p += v0;
    if (base + 1 < SCAN_T) cntAC[base + 1] = p; p += v1;
    if (base + 2 < SCAN_T) cntAC[base + 2] = p; p += v2;
    if (base + 3 < SCAN_T) cntAC[base + 3] = p;
}

__global__ __launch_bounds__(256) void scanB_kernel(int* __restrict__ bsum, int nb) {
    __shared__ int sd[256];
    int t = threadIdx.x;
    int v = (t < nb) ? bsum[t] : 0;
    sd[t] = v;
    __syncthreads();
    for (int off = 1; off < 256; off <<= 1) {
        int xx = (t >= off) ? sd[t - off] : 0;
        __syncthreads();
        sd[t] += xx;
        __syncthreads();
    }
    if (t < nb) bsum[t] = sd[t] - v;  // exclusive
}

__global__ __launch_bounds__(256) void scanC_kernel(int* __restrict__ cntAC,
                                                    const int* __restrict__ bsum,
                                                    int* __restrict__ row_off) {
    int idx = blockIdx.x * 256 + threadIdx.x;
    if (idx < SCAN_T) cntAC[idx] += bsum[idx >> 10];
    if (idx == 0) row_off[NN] = EE;
}

__global__ __launch_bounds__(256) void bucket_scatter_kernel(
    const int* __restrict__ src, const int* __restrict__ dst,
    const int* __restrict__ cntAC, int* __restrict__ eed) {
    __shared__ int lcur[NBUCK];
    int c = blockIdx.x, t = threadIdx.x;
    for (int j = t; j < NBUCK; j += 256) lcur[j] = cntAC[j * NCHUNK + c];
    __syncthreads();
    int beg = c * EPB, end = beg + EPB;
    if (end > EE) end = EE;
    for (int i = beg + t; i < end; i += 256) {
        int d = dst[i];
        int s = src[i];
        int pos = atomicAdd(&lcur[d >> 8], 1);
        eed[pos] = (s << 8) | (d & 255);
    }
}

__global__ __launch_bounds__(1024) void csr_fine_kernel(
    const int* __restrict__ eed, const int* __restrict__ cntAC,
    int* __restrict__ row_off, int* __restrict__ csr_src) {
    int b = blockIdx.x, t = threadIdx.x;
    int bb = cntAC[b * NCHUNK];
    int be = (b + 1 < NBUCK) ? cntAC[(b + 1) * NCHUNK] : EE;
    __shared__ int lcnt[256], lscan[256], lcur[256];
    __shared__ int stage[FCAP];
    if (t < 256) lcnt[t] = 0;
    __syncthreads();
    for (int i = bb + t; i < be; i += 1024) {
        int w = eed[i];
        int off = i - bb;
        if (off < FCAP) stage[off] = w;
        atomicAdd(&lcnt[w & 255], 1);
    }
    __syncthreads();
    if (t < 256) lscan[t] = lcnt[t];
    __syncthreads();
    for (int off = 1; off < 256; off <<= 1) {
        int xx = 0;
        if (t < 256 && t >= off) xx = lscan[t - off];
        __syncthreads();
        if (t < 256) lscan[t] += xx;
        __syncthreads();
    }
    if (t < 256) {
        int excl = lscan[t] - lcnt[t];
        lcur[t] = excl;
        int node = (b << 8) + t;
        if (node < NN) row_off[node] = bb + excl;
    }
    __syncthreads();
    for (int i = bb + t; i < be; i += 1024) {
        int off = i - bb;
        int w = (off < FCAP) ? stage[off] : eed[i];
        int pos = bb + atomicAdd(&lcur[w & 255], 1);
        csr_src[pos] = w >> 8;
    }
}

// ---------------- GAT: wave per dst node, 8 edges/iter, 8-lane groups each
// covering 8 cols via one fp16x8 (uint4) gather. fp32 accumulate. Explicit
// 1-stage pipeline (depth-2 on indices, depth-1 on data) — load-bearing:
// hipcc does NOT hoist gathers across iterations (r12 regression 60->68us).
// unroll 2 lets copy-prop delete the rotation movs (same pipeline depth).
// Guarded index loads (r15 showed unguarded slack loads cost FETCH+VGPR). ---
__global__ __launch_bounds__(256) void gat_kernel(
    const __half* __restrict__ Xh,  // hw fp16 [N][64]
    const float* __restrict__ asn, const float* __restrict__ adn,
    const int* __restrict__ row_off, const int* __restrict__ csr_src,
    const float* __restrict__ bias, float* __restrict__ Y,
    const float* __restrict__ gate_w, const float* __restrict__ gate_b,
    float* __restrict__ gatebuf) {
    int t = threadIdx.x;
    int wave = t >> 6, lane = t & 63;
    int v = blockIdx.x * 4 + wave;
    if (v >= NN) return;
    int grp = lane >> 3, sl = lane & 7;   // 8 groups x 8 lanes
    const uint4* __restrict__ X8 = (const uint4*)Xh;  // 8 halves per uint4
    float adv = adn[v];
    float es = asn[v] + adv;
    es = (es >= 0.f) ? es : 0.2f * es;
    float exs = __expf(es);
    float acc[8];
#pragma unroll
    for (int j = 0; j < 8; ++j) acc[j] = 0.f;
    float den = 0.f;
    if (grp == 0) {  // self loop owned by group 0
        uint4 xw = X8[v * 8 + sl];
        const __half2* hp = (const __half2*)&xw;
#pragma unroll
        for (int j = 0; j < 4; ++j) {
            float2 f = __half22float2(hp[j]);
            acc[2 * j] = exs * f.x;
            acc[2 * j + 1] = exs * f.y;
        }
        den = exs;
    }
    int beg = row_off[v], end = row_off[v + 1];
    // pipeline prologue
    int eA = beg + grp, eB = beg + 8 + grp;
    bool vA = eA < end, vB = eB < end;
    int sA = vA ? csr_src[eA] : v;
    int sB = vB ? csr_src[eB] : v;
    float asvA = asn[sA];
    uint4 xA = X8[sA * 8 + sl];
#pragma unroll 2
    for (int i = beg; i < end; i += 8) {
        // prefetch: index for i+16, data for i+8
        int eC = i + 16 + grp;
        bool vC = eC < end;
        int sC = vC ? csr_src[eC] : v;
        float asvB = asn[sB];
        uint4 xB = X8[sB * 8 + sl];
        // compute on A (landed a full iteration ago)
        float ee = asvA + adv;
        ee = (ee >= 0.f) ? ee : 0.2f * ee;
        float ex = vA ? __expf(ee) : 0.f;
        const __half2* hp = (const __half2*)&xA;
#pragma unroll
        for (int j = 0; j < 4; ++j) {
            float2 f = __half22float2(hp[j]);
            acc[2 * j] = fmaf(ex, f.x, acc[2 * j]);
            acc[2 * j + 1] = fmaf(ex, f.y, acc[2 * j + 1]);
        }
        den += ex;
        // shift
        vA = vB; vB = vC;
        sB = sC;
        asvA = asvB;
        xA = xB;
    }
    // reduce across the 8 lane groups (lanes {sl, sl+8, ..., sl+56})
#pragma unroll
    for (int m = 8; m <= 32; m <<= 1) {
#pragma unroll
        for (int j = 0; j < 8; ++j) acc[j] += __shfl_xor(acc[j], m, 64);
        den += __shfl_xor(den, m, 64);
    }
    float inv = 1.f / (den + 1e-16f);
    float o[8];
#pragma unroll
    for (int j = 0; j < 8; ++j)
        o[j] = fmaxf(acc[j] * inv + bias[sl * 8 + j], 0.f);
    if (grp == 0) {
        float4 o0 = make_float4(o[0], o[1], o[2], o[3]);
        float4 o1 = make_float4(o[4], o[5], o[6], o[7]);
        ((float4*)Y)[v * 16 + sl * 2] = o0;
        ((float4*)Y)[v * 16 + sl * 2 + 1] = o1;
    }
    if (gatebuf) {  // fused pool gate (layer 2 only)
        float p = 0.f;
#pragma unroll
        for (int j = 0; j < 8; ++j) p = fmaf(o[j], gate_w[sl * 8 + j], p);
        float gate = wave_sum(p) * 0.125f + gate_b[0];  // each col counted 8x
        if (lane == 0) gatebuf[v] = gate;
    }
}

// ---------------- pool: contiguous strip per wave, register accumulation ----
#define POOL_NPW 32  // nodes per wave
__global__ __launch_bounds__(256) void pool_kernel(
    const float* __restrict__ Hf, const float* __restrict__ gatebuf,
    const int* __restrict__ batch,
    float* __restrict__ acc, float* __restrict__ den) {
    int t = threadIdx.x, wave = t >> 6, lane = t & 63;
    int v0 = (blockIdx.x * 4 + wave) * POOL_NPW;
    if (v0 >= NN) return;
    int vend = v0 + POOL_NPW;
    if (vend > NN) vend = NN;
    int gcur = batch[v0];
    float accr = 0.f, denr = 0.f;
    for (int v = v0; v < vend; ++v) {
        int g = batch[v];
        if (g != gcur) {
            atomicAdd(&acc[gcur * 64 + lane], accr);
            if (lane == 0) atomicAdd(&den[gcur], denr);
            accr = 0.f; denr = 0.f; gcur = g;
        }
        float ex = __expf(gatebuf[v]);
        accr = fmaf(ex, Hf[(size_t)v * 64 + lane], accr);
        denr += ex;
    }
    atomicAdd(&acc[gcur * 64 + lane], accr);
    if (lane == 0) atomicAdd(&den[gcur], denr);
}

// ---------------- pool finalize + LSTM (h0=c0=0) + MLP head ----------------
__global__ __launch_bounds__(256) void head_kernel(
    const float* __restrict__ acc, const float* __restrict__ den,
    const float* __restrict__ w_ih,
    const float* __restrict__ b_ih, const float* __restrict__ b_hh,
    const float* __restrict__ q_w1, const float* __restrict__ q_b1,
    const float* __restrict__ q_w2, const float* __restrict__ q_b2,
    float* __restrict__ out) {
    int g = blockIdx.x, t = threadIdx.x;
    __shared__ float sp[64];
    __shared__ float sg[512];
    __shared__ float sh1[128];
    __shared__ float ss1[64];
    if (t < 64) sp[t] = acc[g * 64 + t] / (den[g] + 1e-16f);
    __syncthreads();
    for (int r = t; r < 512; r += 256) {
        const float* wr = w_ih + (size_t)r * 64;
        float a = b_ih[r] + b_hh[r];
#pragma unroll
        for (int k = 0; k < 64; ++k) a += sp[k] * wr[k];
        sg[r] = a;
    }
    __syncthreads();
    if (t < 128) {
        float ig = sg[t], gg = sg[256 + t], og = sg[384 + t];
        float c1 = sigmoidf(ig) * tanhf(gg);  // sigmoid(f)*c0 == 0
        float h1 = sigmoidf(og) * tanhf(c1);
        sh1[t] = h1;
        out[640 + g * 128 + t] = h1;
        out[640 + 8192 + g * 128 + t] = c1;
    }
    __syncthreads();
    if (t < 64) {
        float a = q_b1[t];
#pragma unroll
        for (int k = 0; k < 128; ++k) a += sh1[k] * q_w1[k * 64 + t];
        ss1[t] = fmaxf(a, 0.f);
    }
    __syncthreads();
    if (t < 10) {
        float a = q_b2[t];
#pragma unroll
        for (int k = 0; k < 64; ++k) a += ss1[k] * q_w2[k * 10 + t];
        out[g * 10 + t] = a;
    }
}

// ---------------- launcher ----------------
extern "C" void kernel_launch(void* const* d_in, const int* in_sizes, int n_in,
                              void* d_out, int out_size, void* d_ws, size_t ws_size,
                              hipStream_t stream) {
    const float* x = (const float*)d_in[0];
    const int* edge_index = (const int*)d_in[1];
    const int* batch = (const int*)d_in[2];
    const float* enc_w = (const float*)d_in[3];
    const float* enc_b = (const float*)d_in[4];
    const float* ln_g = (const float*)d_in[5];
    const float* ln_b = (const float*)d_in[6];
    const float* w1 = (const float*)d_in[7];
    const float* a1s = (const float*)d_in[8];
    const float* a1d = (const float*)d_in[9];
    const float* b1 = (const float*)d_in[10];
    const float* w2 = (const float*)d_in[11];
    const float* a2s = (const float*)d_in[12];
    const float* a2d = (const float*)d_in[13];
    const float* b2 = (const float*)d_in[14];
    const float* gate_w = (const float*)d_in[15];
    const float* gate_b = (const float*)d_in[16];
    const float* w_ih = (const float*)d_in[17];
    // d_in[18] = w_hh unused (h0 = 0)
    const float* b_ih = (const float*)d_in[19];
    const float* b_hh = (const float*)d_in[20];
    const float* q_w1 = (const float*)d_in[21];
    const float* q_b1 = (const float*)d_in[22];
    const float* q_w2 = (const float*)d_in[23];
    const float* q_b2 = (const float*)d_in[24];
    float* out = (float*)d_out;

    const int* e_src = edge_index;
    const int* e_dst = edge_index + EE;

    // workspace carve-up
    char* ws = (char*)d_ws;
    size_t off = 0;
    auto alloc = [&](size_t bytes) {
        size_t r = off;
        off = (off + bytes + 255) & ~(size_t)255;
        return r;
    };
    float* bufA = (float*)(ws + alloc((size_t)NN * 64 * 4));
    float* bufB = (float*)(ws + alloc((size_t)NN * 64 * 4));
    __half* Xh = (__half*)(ws + alloc((size_t)NN * 64 * 2));
    float* as_n = (float*)(ws + alloc((size_t)NN * 4));
    float* ad_n = (float*)(ws + alloc((size_t)NN * 4));
    float* gatebuf = (float*)(ws + alloc((size_t)NN * 4));
    int* row_off = (int*)(ws + alloc((size_t)(NN + 1) * 4));
    int* csr_src = (int*)(ws + alloc((size_t)EE * 4));
    int* cntAC = (int*)(ws + alloc((size_t)SCAN_T * 4));
    int* bsum = (int*)(ws + alloc((size_t)SCAN_NB * 4));
    float* pacc = (float*)(ws + alloc((size_t)GG * 64 * 4));
    float* pden = (float*)(ws + alloc((size_t)GG * 4));
    // packed edge array aliases bufB (dead before gat layer 1 writes bufB)
    int* eed = (int*)bufB;
    (void)ws_size;

    const int nodeBlocks = (NN + 3) / 4;  // wave per node
    const int mmBlocks = (NN + MM_NPB - 1) / MM_NPB;
    const int poolBlocks = (NN + 4 * POOL_NPW - 1) / (4 * POOL_NPW);
    const int scanCBlocks = (SCAN_T + 255) / 256;

    // CSR by dst via bucket sort (LDS atomics only; reused by both GAT layers)
    bucket_count_kernel<<<NCHUNK, 256, 0, stream>>>(e_dst, cntAC);
    scanA_kernel<<<SCAN_NB, 256, 0, stream>>>(cntAC, bsum);
    scanB_kernel<<<1, 256, 0, stream>>>(bsum, SCAN_NB);
    scanC_kernel<<<scanCBlocks, 256, 0, stream>>>(cntAC, bsum, row_off);
    bucket_scatter_kernel<<<NCHUNK, 256, 0, stream>>>(e_src, e_dst, cntAC, eed);
    csr_fine_kernel<<<NBUCK, 1024, 0, stream>>>(eed, cntAC, row_off, csr_src);

    // GAT layer 1: fused enc+mm -> fp16 Xh -> gat -> bufB(h1)
    encmm_kernel<<<mmBlocks, 256, 0, stream>>>(x, enc_w, enc_b, ln_g, ln_b,
                                               w1, a1s, a1d, Xh, as_n, ad_n);
    gat_kernel<<<nodeBlocks, 256, 0, stream>>>(Xh, as_n, ad_n, row_off, csr_src,
                                               b1, bufB, nullptr, nullptr, nullptr);

    // GAT layer 2: bufB -> fp16 Xh -> gat -> bufA(h2), fused pool gate
    mm_kernel<<<mmBlocks, 256, 0, stream>>>(bufB, w2, a2s, a2d, Xh, as_n, ad_n);
    gat_kernel<<<nodeBlocks, 256, 0, stream>>>(Xh, as_n, ad_n, row_off, csr_src,
                                               b2, bufA, gate_w, gate_b, gatebuf);

    // pool: register-accumulated partial sums, flush-on-graph-change atomics
    hipMemsetAsync(pacc, 0, (size_t)(GG * 64 + GG) * 4 + 256, stream);
    pool_kernel<<<poolBlocks, 256, 0, stream>>>(bufA, gatebuf, batch, pacc, pden);

    // LSTM + MLP head (pool finalize fused)
    head_kernel<<<GG, 256, 0, stream>>>(pacc, pden, w_ih, b_ih, b_hh,
                                        q_w1, q_b1, q_w2, q_b2, out);
}

// Round 17
// 235.141 us; speedup vs baseline: 1.1134x; 1.0412x over previous
//
#include <hip/hip_runtime.h>
#include <hip/hip_fp16.h>
#include <math.h>

#define NN 100000
#define EE 1600000
#define GG 64
#define HH 64
#define LHH 128
#define AA 10

#define NBUCK 391            // ceil(NN/256): 256 dst nodes per bucket
#define EPB 8192             // edges per chunk
#define NCHUNK 196           // ceil(EE/EPB)
#define SCAN_T (NBUCK * NCHUNK)               // 76636
#define SCAN_NB ((SCAN_T + 1023) / 1024)      // 75
#define FCAP 8192            // LDS staging capacity in csr_fine (max bucket ~4500)
#define MM_NPB 16            // nodes per block in encmm (4 waves x 4 nodes)

typedef _Float16 f16;
typedef f16 f16x8 __attribute__((ext_vector_type(8)));
typedef float f32x4 __attribute__((ext_vector_type(4)));

// ---------------- helpers ----------------
__device__ __forceinline__ float wave_sum(float v) {
#pragma unroll
    for (int m = 32; m >= 1; m >>= 1) v += __shfl_xor(v, m, 64);
    return v;
}
__device__ __forceinline__ float sigmoidf(float x) { return 1.f / (1.f + expf(-x)); }

// ---------------- fused encoder + mm1: h = LN(relu(x@enc_w+enc_b));
// hw = h@W -> fp16 Xh; as/ad dots. h never touches global memory. ----------
__global__ __launch_bounds__(256) void encmm_kernel(
    const float* __restrict__ x, const float* __restrict__ enc_w,
    const float* __restrict__ enc_b, const float* __restrict__ ln_g,
    const float* __restrict__ ln_b,
    const float* __restrict__ W, const float* __restrict__ avs,
    const float* __restrict__ avd, __half* __restrict__ Xh,
    float* __restrict__ as_out, float* __restrict__ ad_out) {
    __shared__ float4 sW4[64 * 16];     // 16 KB
    __shared__ float srow[MM_NPB][68];  // 64 cols + 4 pad
    __shared__ float sw[5 * 64];
    int t = threadIdx.x;
    const float4* __restrict__ W4 = (const float4*)W;
#pragma unroll
    for (int i = t; i < 1024; i += 256) sW4[i] = W4[i];
    for (int i = t; i < 320; i += 256) sw[i] = enc_w[i];
    __syncthreads();
    int wave = t >> 6, lane = t & 63;
    int vbase = blockIdx.x * MM_NPB;
    float eb = enc_b[lane], lg = ln_g[lane], lb = ln_b[lane];
    // encoder: each wave computes its 4 nodes into srow
#pragma unroll
    for (int p = 0; p < 4; ++p) {
        int vl = wave * 4 + p;
        int v = vbase + vl;
        if (v < NN) {
            float a = eb;
#pragma unroll
            for (int k = 0; k < 5; ++k) a += x[v * 5 + k] * sw[k * 64 + lane];
            a = fmaxf(a, 0.f);
            float mu = wave_sum(a) * (1.f / 64.f);
            float d = a - mu;
            float var = wave_sum(d * d) * (1.f / 64.f);
            float r = 1.f / sqrtf(var + 1e-5f);
            srow[vl][lane] = d * r * lg + lb;
        }
    }
    __syncthreads();
    // mm: wave handles 4 nodes; lane = (grp: node, sl: 4-col float4)
    int grp = lane >> 4, sl = lane & 15;
    int vl = wave * 4 + grp;
    int v = vbase + vl;
    if (v >= NN) return;
    float4 acc = make_float4(0.f, 0.f, 0.f, 0.f);
#pragma unroll
    for (int k4 = 0; k4 < 16; ++k4) {
        float4 h4 = *(const float4*)&srow[vl][k4 * 4];
        float4 w0 = sW4[(k4 * 4 + 0) * 16 + sl];
        float4 w1 = sW4[(k4 * 4 + 1) * 16 + sl];
        float4 w2 = sW4[(k4 * 4 + 2) * 16 + sl];
        float4 w3 = sW4[(k4 * 4 + 3) * 16 + sl];
        acc.x = fmaf(h4.x, w0.x, acc.x);
        acc.y = fmaf(h4.x, w0.y, acc.y);
        acc.z = fmaf(h4.x, w0.z, acc.z);
        acc.w = fmaf(h4.x, w0.w, acc.w);
        acc.x = fmaf(h4.y, w1.x, acc.x);
        acc.y = fmaf(h4.y, w1.y, acc.y);
        acc.z = fmaf(h4.y, w1.z, acc.z);
        acc.w = fmaf(h4.y, w1.w, acc.w);
        acc.x = fmaf(h4.z, w2.x, acc.x);
        acc.y = fmaf(h4.z, w2.y, acc.y);
        acc.z = fmaf(h4.z, w2.z, acc.z);
        acc.w = fmaf(h4.z, w2.w, acc.w);
        acc.x = fmaf(h4.w, w3.x, acc.x);
        acc.y = fmaf(h4.w, w3.y, acc.y);
        acc.z = fmaf(h4.w, w3.z, acc.z);
        acc.w = fmaf(h4.w, w3.w, acc.w);
    }
    float4 s4 = ((const float4*)avs)[sl];
    float4 d4 = ((const float4*)avd)[sl];
    float pa = acc.x * s4.x + acc.y * s4.y + acc.z * s4.z + acc.w * s4.w;
    float pd = acc.x * d4.x + acc.y * d4.y + acc.z * d4.z + acc.w * d4.w;
#pragma unroll
    for (int m = 1; m <= 8; m <<= 1) {
        pa += __shfl_xor(pa, m, 64);
        pd += __shfl_xor(pd, m, 64);
    }
    if (sl == 0) { as_out[v] = pa; ad_out[v] = pd; }
    __half2 lo = __floats2half2_rn(acc.x, acc.y);
    __half2 hi = __floats2half2_rn(acc.z, acc.w);
    uint2 pk;
    pk.x = *(unsigned int*)&lo;
    pk.y = *(unsigned int*)&hi;
    ((uint2*)Xh)[(size_t)v * 16 + sl] = pk;
}

// ---------------- mm (layer 2) via MFMA: wave = 16-node tile, all 64 cols.
// W held in registers (16 f16x8 fragments, loaded once); A from global
// float4 + cvt. 8 x mfma_f32_16x16x32_f16 per tile. D layout (m89):
// col=lane&15, row=(lane>>4)*4+reg. ----------------------------------------
__global__ __launch_bounds__(256) void mm_mfma_kernel(
    const float* __restrict__ buf, const float* __restrict__ W,
    const float* __restrict__ avs, const float* __restrict__ avd,
    __half* __restrict__ Xh,
    float* __restrict__ as_out, float* __restrict__ ad_out) {
    int t = threadIdx.x;
    int wave = t >> 6, lane = t & 63;
    int m0 = (blockIdx.x * 4 + wave) * 16;
    if (m0 >= NN) return;           // NN % 16 == 0: full tiles only
    int lr = lane & 15;             // row (A) / col (B,D)
    int lg = lane >> 4;             // k lane-group
    // B fragments: bf[kt][n][j] = W[kt*32 + lg*8 + j][n*16 + lr]
    f16x8 bf[2][4];
#pragma unroll
    for (int kt = 0; kt < 2; ++kt)
#pragma unroll
        for (int n = 0; n < 4; ++n)
#pragma unroll
            for (int j = 0; j < 8; ++j)
                bf[kt][n][j] = (f16)W[(kt * 32 + lg * 8 + j) * 64 + n * 16 + lr];
    // A fragments: af[kt][j] = buf[m0+lr][kt*32 + lg*8 + j]
    const float4* __restrict__ buf4 = (const float4*)buf;
    f16x8 af[2];
#pragma unroll
    for (int kt = 0; kt < 2; ++kt) {
        float4 a0 = buf4[(size_t)(m0 + lr) * 16 + kt * 8 + lg * 2];
        float4 a1 = buf4[(size_t)(m0 + lr) * 16 + kt * 8 + lg * 2 + 1];
        af[kt][0] = (f16)a0.x; af[kt][1] = (f16)a0.y;
        af[kt][2] = (f16)a0.z; af[kt][3] = (f16)a0.w;
        af[kt][4] = (f16)a1.x; af[kt][5] = (f16)a1.y;
        af[kt][6] = (f16)a1.z; af[kt][7] = (f16)a1.w;
    }
    // D = A*W, accumulate across kt (K-loop accumulator recipe)
    f32x4 d[4];
#pragma unroll
    for (int n = 0; n < 4; ++n) {
        f32x4 dn = {0.f, 0.f, 0.f, 0.f};
#pragma unroll
        for (int kt = 0; kt < 2; ++kt)
            dn = __builtin_amdgcn_mfma_f32_16x16x32_f16(af[kt], bf[kt][n], dn, 0, 0, 0);
        d[n] = dn;
    }
    // store Xh fp16: lane holds d[n][j] = hw[m0 + lg*4 + j][n*16 + lr]
#pragma unroll
    for (int n = 0; n < 4; ++n)
#pragma unroll
        for (int j = 0; j < 4; ++j)
            Xh[(size_t)(m0 + lg * 4 + j) * 64 + n * 16 + lr] = __float2half(d[n][j]);
    // as/ad: per-row dot with avs/avd, reduce across the 16 col-lanes
    float pa[4] = {0.f, 0.f, 0.f, 0.f}, pd[4] = {0.f, 0.f, 0.f, 0.f};
#pragma unroll
    for (int n = 0; n < 4; ++n) {
        float sv = avs[n * 16 + lr], dv = avd[n * 16 + lr];
#pragma unroll
        for (int j = 0; j < 4; ++j) {
            pa[j] = fmaf(d[n][j], sv, pa[j]);
            pd[j] = fmaf(d[n][j], dv, pd[j]);
        }
    }
#pragma unroll
    for (int m = 1; m <= 8; m <<= 1) {
#pragma unroll
        for (int j = 0; j < 4; ++j) {
            pa[j] += __shfl_xor(pa[j], m, 64);
            pd[j] += __shfl_xor(pd[j], m, 64);
        }
    }
    if (lr == 0) {
#pragma unroll
        for (int j = 0; j < 4; ++j) {
            as_out[m0 + lg * 4 + j] = pa[j];
            ad_out[m0 + lg * 4 + j] = pd[j];
        }
    }
}

// ---------------- CSR build: bucket sort (LDS atomics only) ----------------
__global__ __launch_bounds__(256) void bucket_count_kernel(const int* __restrict__ dst,
                                                           int* __restrict__ cntAC) {
    __shared__ int lcnt[NBUCK];
    int c = blockIdx.x, t = threadIdx.x;
    for (int j = t; j < NBUCK; j += 256) lcnt[j] = 0;
    __syncthreads();
    int beg = c * EPB, end = beg + EPB;
    if (end > EE) end = EE;
    for (int i = beg + t; i < end; i += 256) atomicAdd(&lcnt[dst[i] >> 8], 1);
    __syncthreads();
    for (int j = t; j < NBUCK; j += 256) cntAC[j * NCHUNK + c] = lcnt[j];
}

__global__ __launch_bounds__(256) void scanA_kernel(int* __restrict__ cntAC,
                                                    int* __restrict__ bsum) {
    __shared__ int sd[256];
    int t = threadIdx.x, b = blockIdx.x;
    int base = b * 1024 + t * 4;
    int v0 = (base + 0 < SCAN_T) ? cntAC[base + 0] : 0;
    int v1 = (base + 1 < SCAN_T) ? cntAC[base + 1] : 0;
    int v2 = (base + 2 < SCAN_T) ? cntAC[base + 2] : 0;
    int v3 = (base + 3 < SCAN_T) ? cntAC[base + 3] : 0;
    int tot = v0 + v1 + v2 + v3;
    sd[t] = tot;
    __syncthreads();
    for (int off = 1; off < 256; off <<= 1) {
        int xx = (t >= off) ? sd[t - off] : 0;
        __syncthreads();
        sd[t] += xx;
        __syncthreads();
    }
    int p = sd[t] - tot;  // exclusive within block
    if (t == 255) bsum[b] = sd[255];
    if (base + 0 < SCAN_T) cntAC[base + 0] = p; p += v0;
    if (base + 1 < SCAN_T) cntAC[base + 1] = p; p += v1;
    if (base + 2 < SCAN_T) cntAC[base + 2] = p; p += v2;
    if (base + 3 < SCAN_T) cntAC[base + 3] = p;
}

__global__ __launch_bounds__(256) void scanB_kernel(int* __restrict__ bsum, int nb) {
    __shared__ int sd[256];
    int t = threadIdx.x;
    int v = (t < nb) ? bsum[t] : 0;
    sd[t] = v;
    __syncthreads();
    for (int off = 1; off < 256; off <<= 1) {
        int xx = (t >= off) ? sd[t - off] : 0;
        __syncthreads();
        sd[t] += xx;
        __syncthreads();
    }
    if (t < nb) bsum[t] = sd[t] - v;  // exclusive
}

__global__ __launch_bounds__(256) void scanC_kernel(int* __restrict__ cntAC,
                                                    const int* __restrict__ bsum,
                                                    int* __restrict__ row_off) {
    int idx = blockIdx.x * 256 + threadIdx.x;
    if (idx < SCAN_T) cntAC[idx] += bsum[idx >> 10];
    if (idx == 0) row_off[NN] = EE;
}

__global__ __launch_bounds__(256) void bucket_scatter_kernel(
    const int* __restrict__ src, const int* __restrict__ dst,
    const int* __restrict__ cntAC, int* __restrict__ eed) {
    __shared__ int lcur[NBUCK];
    int c = blockIdx.x, t = threadIdx.x;
    for (int j = t; j < NBUCK; j += 256) lcur[j] = cntAC[j * NCHUNK + c];
    __syncthreads();
    int beg = c * EPB, end = beg + EPB;
    if (end > EE) end = EE;
    for (int i = beg + t; i < end; i += 256) {
        int d = dst[i];
        int s = src[i];
        int pos = atomicAdd(&lcur[d >> 8], 1);
        eed[pos] = (s << 8) | (d & 255);
    }
}

__global__ __launch_bounds__(1024) void csr_fine_kernel(
    const int* __restrict__ eed, const int* __restrict__ cntAC,
    int* __restrict__ row_off, int* __restrict__ csr_src) {
    int b = blockIdx.x, t = threadIdx.x;
    int bb = cntAC[b * NCHUNK];
    int be = (b + 1 < NBUCK) ? cntAC[(b + 1) * NCHUNK] : EE;
    __shared__ int lcnt[256], lscan[256], lcur[256];
    __shared__ int stage[FCAP];
    if (t < 256) lcnt[t] = 0;
    __syncthreads();
    for (int i = bb + t; i < be; i += 1024) {
        int w = eed[i];
        int off = i - bb;
        if (off < FCAP) stage[off] = w;
        atomicAdd(&lcnt[w & 255], 1);
    }
    __syncthreads();
    if (t < 256) lscan[t] = lcnt[t];
    __syncthreads();
    for (int off = 1; off < 256; off <<= 1) {
        int xx = 0;
        if (t < 256 && t >= off) xx = lscan[t - off];
        __syncthreads();
        if (t < 256) lscan[t] += xx;
        __syncthreads();
    }
    if (t < 256) {
        int excl = lscan[t] - lcnt[t];
        lcur[t] = excl;
        int node = (b << 8) + t;
        if (node < NN) row_off[node] = bb + excl;
    }
    __syncthreads();
    for (int i = bb + t; i < be; i += 1024) {
        int off = i - bb;
        int w = (off < FCAP) ? stage[off] : eed[i];
        int pos = bb + atomicAdd(&lcur[w & 255], 1);
        csr_src[pos] = w >> 8;
    }
}

// ---------------- GAT: wave per dst node, 8 edges/iter, 8-lane groups each
// covering 8 cols via one fp16x8 (uint4) gather. fp32 accumulate. Explicit
// 1-stage pipeline (depth-2 on indices, depth-1 on data) — load-bearing:
// hipcc does NOT hoist gathers across iterations (r12 regression 60->68us).
// unroll 2 lets copy-prop delete the rotation movs (same pipeline depth).
// Guarded index loads (r15 showed unguarded slack loads cost FETCH+VGPR). ---
__global__ __launch_bounds__(256) void gat_kernel(
    const __half* __restrict__ Xh,  // hw fp16 [N][64]
    const float* __restrict__ asn, const float* __restrict__ adn,
    const int* __restrict__ row_off, const int* __restrict__ csr_src,
    const float* __restrict__ bias, float* __restrict__ Y,
    const float* __restrict__ gate_w, const float* __restrict__ gate_b,
    float* __restrict__ gatebuf) {
    int t = threadIdx.x;
    int wave = t >> 6, lane = t & 63;
    int v = blockIdx.x * 4 + wave;
    if (v >= NN) return;
    int grp = lane >> 3, sl = lane & 7;   // 8 groups x 8 lanes
    const uint4* __restrict__ X8 = (const uint4*)Xh;  // 8 halves per uint4
    float adv = adn[v];
    float es = asn[v] + adv;
    es = (es >= 0.f) ? es : 0.2f * es;
    float exs = __expf(es);
    float acc[8];
#pragma unroll
    for (int j = 0; j < 8; ++j) acc[j] = 0.f;
    float den = 0.f;
    if (grp == 0) {  // self loop owned by group 0
        uint4 xw = X8[v * 8 + sl];
        const __half2* hp = (const __half2*)&xw;
#pragma unroll
        for (int j = 0; j < 4; ++j) {
            float2 f = __half22float2(hp[j]);
            acc[2 * j] = exs * f.x;
            acc[2 * j + 1] = exs * f.y;
        }
        den = exs;
    }
    int beg = row_off[v], end = row_off[v + 1];
    // pipeline prologue
    int eA = beg + grp, eB = beg + 8 + grp;
    bool vA = eA < end, vB = eB < end;
    int sA = vA ? csr_src[eA] : v;
    int sB = vB ? csr_src[eB] : v;
    float asvA = asn[sA];
    uint4 xA = X8[sA * 8 + sl];
#pragma unroll 2
    for (int i = beg; i < end; i += 8) {
        // prefetch: index for i+16, data for i+8
        int eC = i + 16 + grp;
        bool vC = eC < end;
        int sC = vC ? csr_src[eC] : v;
        float asvB = asn[sB];
        uint4 xB = X8[sB * 8 + sl];
        // compute on A (landed a full iteration ago)
        float ee = asvA + adv;
        ee = (ee >= 0.f) ? ee : 0.2f * ee;
        float ex = vA ? __expf(ee) : 0.f;
        const __half2* hp = (const __half2*)&xA;
#pragma unroll
        for (int j = 0; j < 4; ++j) {
            float2 f = __half22float2(hp[j]);
            acc[2 * j] = fmaf(ex, f.x, acc[2 * j]);
            acc[2 * j + 1] = fmaf(ex, f.y, acc[2 * j + 1]);
        }
        den += ex;
        // shift
        vA = vB; vB = vC;
        sB = sC;
        asvA = asvB;
        xA = xB;
    }
    // reduce across the 8 lane groups (lanes {sl, sl+8, ..., sl+56})
#pragma unroll
    for (int m = 8; m <= 32; m <<= 1) {
#pragma unroll
        for (int j = 0; j < 8; ++j) acc[j] += __shfl_xor(acc[j], m, 64);
        den += __shfl_xor(den, m, 64);
    }
    float inv = 1.f / (den + 1e-16f);
    float o[8];
#pragma unroll
    for (int j = 0; j < 8; ++j)
        o[j] = fmaxf(acc[j] * inv + bias[sl * 8 + j], 0.f);
    if (grp == 0) {
        float4 o0 = make_float4(o[0], o[1], o[2], o[3]);
        float4 o1 = make_float4(o[4], o[5], o[6], o[7]);
        ((float4*)Y)[v * 16 + sl * 2] = o0;
        ((float4*)Y)[v * 16 + sl * 2 + 1] = o1;
    }
    if (gatebuf) {  // fused pool gate (layer 2 only)
        float p = 0.f;
#pragma unroll
        for (int j = 0; j < 8; ++j) p = fmaf(o[j], gate_w[sl * 8 + j], p);
        float gate = wave_sum(p) * 0.125f + gate_b[0];  // each col counted 8x
        if (lane == 0) gatebuf[v] = gate;
    }
}

// ---------------- pool: contiguous strip per wave, register accumulation ----
#define POOL_NPW 32  // nodes per wave
__global__ __launch_bounds__(256) void pool_kernel(
    const float* __restrict__ Hf, const float* __restrict__ gatebuf,
    const int* __restrict__ batch,
    float* __restrict__ acc, float* __restrict__ den) {
    int t = threadIdx.x, wave = t >> 6, lane = t & 63;
    int v0 = (blockIdx.x * 4 + wave) * POOL_NPW;
    if (v0 >= NN) return;
    int vend = v0 + POOL_NPW;
    if (vend > NN) vend = NN;
    int gcur = batch[v0];
    float accr = 0.f, denr = 0.f;
    for (int v = v0; v < vend; ++v) {
        int g = batch[v];
        if (g != gcur) {
            atomicAdd(&acc[gcur * 64 + lane], accr);
            if (lane == 0) atomicAdd(&den[gcur], denr);
            accr = 0.f; denr = 0.f; gcur = g;
        }
        float ex = __expf(gatebuf[v]);
        accr = fmaf(ex, Hf[(size_t)v * 64 + lane], accr);
        denr += ex;
    }
    atomicAdd(&acc[gcur * 64 + lane], accr);
    if (lane == 0) atomicAdd(&den[gcur], denr);
}

// ---------------- pool finalize + LSTM (h0=c0=0) + MLP head ----------------
__global__ __launch_bounds__(256) void head_kernel(
    const float* __restrict__ acc, const float* __restrict__ den,
    const float* __restrict__ w_ih,
    const float* __restrict__ b_ih, const float* __restrict__ b_hh,
    const float* __restrict__ q_w1, const float* __restrict__ q_b1,
    const float* __restrict__ q_w2, const float* __restrict__ q_b2,
    float* __restrict__ out) {
    int g = blockIdx.x, t = threadIdx.x;
    __shared__ float sp[64];
    __shared__ float sg[512];
    __shared__ float sh1[128];
    __shared__ float ss1[64];
    if (t < 64) sp[t] = acc[g * 64 + t] / (den[g] + 1e-16f);
    __syncthreads();
    for (int r = t; r < 512; r += 256) {
        const float* wr = w_ih + (size_t)r * 64;
        float a = b_ih[r] + b_hh[r];
#pragma unroll
        for (int k = 0; k < 64; ++k) a += sp[k] * wr[k];
        sg[r] = a;
    }
    __syncthreads();
    if (t < 128) {
        float ig = sg[t], gg = sg[256 + t], og = sg[384 + t];
        float c1 = sigmoidf(ig) * tanhf(gg);  // sigmoid(f)*c0 == 0
        float h1 = sigmoidf(og) * tanhf(c1);
        sh1[t] = h1;
        out[640 + g * 128 + t] = h1;
        out[640 + 8192 + g * 128 + t] = c1;
    }
    __syncthreads();
    if (t < 64) {
        float a = q_b1[t];
#pragma unroll
        for (int k = 0; k < 128; ++k) a += sh1[k] * q_w1[k * 64 + t];
        ss1[t] = fmaxf(a, 0.f);
    }
    __syncthreads();
    if (t < 10) {
        float a = q_b2[t];
#pragma unroll
        for (int k = 0; k < 64; ++k) a += ss1[k] * q_w2[k * 10 + t];
        out[g * 10 + t] = a;
    }
}

// ---------------- launcher ----------------
extern "C" void kernel_launch(void* const* d_in, const int* in_sizes, int n_in,
                              void* d_out, int out_size, void* d_ws, size_t ws_size,
                              hipStream_t stream) {
    const float* x = (const float*)d_in[0];
    const int* edge_index = (const int*)d_in[1];
    const int* batch = (const int*)d_in[2];
    const float* enc_w = (const float*)d_in[3];
    const float* enc_b = (const float*)d_in[4];
    const float* ln_g = (const float*)d_in[5];
    const float* ln_b = (const float*)d_in[6];
    const float* w1 = (const float*)d_in[7];
    const float* a1s = (const float*)d_in[8];
    const float* a1d = (const float*)d_in[9];
    const float* b1 = (const float*)d_in[10];
    const float* w2 = (const float*)d_in[11];
    const float* a2s = (const float*)d_in[12];
    const float* a2d = (const float*)d_in[13];
    const float* b2 = (const float*)d_in[14];
    const float* gate_w = (const float*)d_in[15];
    const float* gate_b = (const float*)d_in[16];
    const float* w_ih = (const float*)d_in[17];
    // d_in[18] = w_hh unused (h0 = 0)
    const float* b_ih = (const float*)d_in[19];
    const float* b_hh = (const float*)d_in[20];
    const float* q_w1 = (const float*)d_in[21];
    const float* q_b1 = (const float*)d_in[22];
    const float* q_w2 = (const float*)d_in[23];
    const float* q_b2 = (const float*)d_in[24];
    float* out = (float*)d_out;

    const int* e_src = edge_index;
    const int* e_dst = edge_index + EE;

    // workspace carve-up
    char* ws = (char*)d_ws;
    size_t off = 0;
    auto alloc = [&](size_t bytes) {
        size_t r = off;
        off = (off + bytes + 255) & ~(size_t)255;
        return r;
    };
    float* bufA = (float*)(ws + alloc((size_t)NN * 64 * 4));
    float* bufB = (float*)(ws + alloc((size_t)NN * 64 * 4));
    __half* Xh = (__half*)(ws + alloc((size_t)NN * 64 * 2));
    float* as_n = (float*)(ws + alloc((size_t)NN * 4));
    float* ad_n = (float*)(ws + alloc((size_t)NN * 4));
    float* gatebuf = (float*)(ws + alloc((size_t)NN * 4));
    int* row_off = (int*)(ws + alloc((size_t)(NN + 1) * 4));
    int* csr_src = (int*)(ws + alloc((size_t)EE * 4));
    int* cntAC = (int*)(ws + alloc((size_t)SCAN_T * 4));
    int* bsum = (int*)(ws + alloc((size_t)SCAN_NB * 4));
    float* pacc = (float*)(ws + alloc((size_t)GG * 64 * 4));
    float* pden = (float*)(ws + alloc((size_t)GG * 4));
    // packed edge array aliases bufB (dead before gat layer 1 writes bufB)
    int* eed = (int*)bufB;
    (void)ws_size;

    const int nodeBlocks = (NN + 3) / 4;  // wave per node
    const int mmBlocks = (NN + MM_NPB - 1) / MM_NPB;
    const int mmMfmaBlocks = (NN / 16 + 3) / 4;  // 1563: wave per 16-node tile
    const int poolBlocks = (NN + 4 * POOL_NPW - 1) / (4 * POOL_NPW);
    const int scanCBlocks = (SCAN_T + 255) / 256;

    // CSR by dst via bucket sort (LDS atomics only; reused by both GAT layers)
    bucket_count_kernel<<<NCHUNK, 256, 0, stream>>>(e_dst, cntAC);
    scanA_kernel<<<SCAN_NB, 256, 0, stream>>>(cntAC, bsum);
    scanB_kernel<<<1, 256, 0, stream>>>(bsum, SCAN_NB);
    scanC_kernel<<<scanCBlocks, 256, 0, stream>>>(cntAC, bsum, row_off);
    bucket_scatter_kernel<<<NCHUNK, 256, 0, stream>>>(e_src, e_dst, cntAC, eed);
    csr_fine_kernel<<<NBUCK, 1024, 0, stream>>>(eed, cntAC, row_off, csr_src);

    // GAT layer 1: fused enc+mm -> fp16 Xh -> gat -> bufB(h1)
    encmm_kernel<<<mmBlocks, 256, 0, stream>>>(x, enc_w, enc_b, ln_g, ln_b,
                                               w1, a1s, a1d, Xh, as_n, ad_n);
    gat_kernel<<<nodeBlocks, 256, 0, stream>>>(Xh, as_n, ad_n, row_off, csr_src,
                                               b1, bufB, nullptr, nullptr, nullptr);

    // GAT layer 2: bufB -> MFMA mm -> fp16 Xh -> gat -> bufA(h2), fused gate
    mm_mfma_kernel<<<mmMfmaBlocks, 256, 0, stream>>>(bufB, w2, a2s, a2d, Xh,
                                                     as_n, ad_n);
    gat_kernel<<<nodeBlocks, 256, 0, stream>>>(Xh, as_n, ad_n, row_off, csr_src,
                                               b2, bufA, gate_w, gate_b, gatebuf);

    // pool: register-accumulated partial sums, flush-on-graph-change atomics
    hipMemsetAsync(pacc, 0, (size_t)(GG * 64 + GG) * 4 + 256, stream);
    pool_kernel<<<poolBlocks, 256, 0, stream>>>(bufA, gatebuf, batch, pacc, pden);

    // LSTM + MLP head (pool finalize fused)
    head_kernel<<<GG, 256, 0, stream>>>(pacc, pden, w_ih, b_ih, b_hh,
                                        q_w1, q_b1, q_w2, q_b2, out);
}

// Round 18
// 221.175 us; speedup vs baseline: 1.1837x; 1.0631x over previous
//
#include <hip/hip_runtime.h>
#include <hip/hip_fp16.h>
#include <math.h>

#define NN 100000
#define EE 1600000
#define GG 64
#define HH 64
#define LHH 128
#define AA 10

#define NBUCK 391            // ceil(NN/256): 256 dst nodes per bucket
#define EPB 8192             // edges per chunk
#define NCHUNK 196           // ceil(EE/EPB)
#define SCAN_T (NBUCK * NCHUNK)               // 76636
#define SCAN_NB ((SCAN_T + 1023) / 1024)      // 75
#define FCAP 8192            // LDS staging capacity in csr_fine (max bucket ~4500)

typedef _Float16 f16;
typedef f16 f16x8 __attribute__((ext_vector_type(8)));
typedef float f32x4 __attribute__((ext_vector_type(4)));

// ---------------- helpers ----------------
__device__ __forceinline__ float wave_sum(float v) {
#pragma unroll
    for (int m = 32; m >= 1; m >>= 1) v += __shfl_xor(v, m, 64);
    return v;
}
__device__ __forceinline__ float sigmoidf(float x) { return 1.f / (1.f + expf(-x)); }

// ---------------- fused encoder + mm1 via MFMA: wave = 16-node tile.
// Encoder (LN) per node into private LDS region (no barrier: same-wave
// write->read), then A from LDS, W1 in registers, 8 x mfma_16x16x32_f16.
// D layout (m89): col=lane&15, row=(lane>>4)*4+reg. ------------------------
__global__ __launch_bounds__(256) void encmm_mfma_kernel(
    const float* __restrict__ x, const float* __restrict__ enc_w,
    const float* __restrict__ enc_b, const float* __restrict__ ln_g,
    const float* __restrict__ ln_b,
    const float* __restrict__ W, const float* __restrict__ avs,
    const float* __restrict__ avd, __half* __restrict__ Xh,
    float* __restrict__ as_out, float* __restrict__ ad_out) {
    __shared__ float srow[4][16][68];  // per-wave region, +4 pad
    __shared__ float sw[5 * 64];
    int t = threadIdx.x;
    for (int i = t; i < 320; i += 256) sw[i] = enc_w[i];
    __syncthreads();
    int wave = t >> 6, lane = t & 63;
    int m0 = (blockIdx.x * 4 + wave) * 16;
    if (m0 >= NN) return;  // NN % 16 == 0: full tiles
    float eb = enc_b[lane], lgm = ln_g[lane], lbb = ln_b[lane];
    // encoder: 16 nodes per wave, lane = column
#pragma unroll 4
    for (int p = 0; p < 16; ++p) {
        int v = m0 + p;
        float a = eb;
#pragma unroll
        for (int k = 0; k < 5; ++k) a += x[v * 5 + k] * sw[k * 64 + lane];
        a = fmaxf(a, 0.f);
        float mu = wave_sum(a) * (1.f / 64.f);
        float d = a - mu;
        float var = wave_sum(d * d) * (1.f / 64.f);
        float r = 1.f / sqrtf(var + 1e-5f);
        srow[wave][p][lane] = d * r * lgm + lbb;
    }
    int lr = lane & 15;  // row (A) / col (B,D)
    int lg = lane >> 4;  // k lane-group
    // B fragments: bf[kt][n][j] = W[kt*32 + lg*8 + j][n*16 + lr]
    f16x8 bf[2][4];
#pragma unroll
    for (int kt = 0; kt < 2; ++kt)
#pragma unroll
        for (int n = 0; n < 4; ++n)
#pragma unroll
            for (int j = 0; j < 8; ++j)
                bf[kt][n][j] = (f16)W[(kt * 32 + lg * 8 + j) * 64 + n * 16 + lr];
    // A fragments from LDS: af[kt][j] = h[m0+lr][kt*32 + lg*8 + j]
    f16x8 af[2];
#pragma unroll
    for (int kt = 0; kt < 2; ++kt)
#pragma unroll
        for (int j = 0; j < 8; ++j)
            af[kt][j] = (f16)srow[wave][lr][kt * 32 + lg * 8 + j];
    // D = A*W, accumulate across kt
    f32x4 d[4];
#pragma unroll
    for (int n = 0; n < 4; ++n) {
        f32x4 dn = {0.f, 0.f, 0.f, 0.f};
#pragma unroll
        for (int kt = 0; kt < 2; ++kt)
            dn = __builtin_amdgcn_mfma_f32_16x16x32_f16(af[kt], bf[kt][n], dn, 0, 0, 0);
        d[n] = dn;
    }
    // store Xh fp16: lane holds d[n][j] = hw[m0 + lg*4 + j][n*16 + lr]
#pragma unroll
    for (int n = 0; n < 4; ++n)
#pragma unroll
        for (int j = 0; j < 4; ++j)
            Xh[(size_t)(m0 + lg * 4 + j) * 64 + n * 16 + lr] = __float2half(d[n][j]);
    // as/ad: per-row dot with avs/avd, reduce across the 16 col-lanes
    float pa[4] = {0.f, 0.f, 0.f, 0.f}, pd[4] = {0.f, 0.f, 0.f, 0.f};
#pragma unroll
    for (int n = 0; n < 4; ++n) {
        float sv = avs[n * 16 + lr], dv = avd[n * 16 + lr];
#pragma unroll
        for (int j = 0; j < 4; ++j) {
            pa[j] = fmaf(d[n][j], sv, pa[j]);
            pd[j] = fmaf(d[n][j], dv, pd[j]);
        }
    }
#pragma unroll
    for (int m = 1; m <= 8; m <<= 1) {
#pragma unroll
        for (int j = 0; j < 4; ++j) {
            pa[j] += __shfl_xor(pa[j], m, 64);
            pd[j] += __shfl_xor(pd[j], m, 64);
        }
    }
    if (lr == 0) {
#pragma unroll
        for (int j = 0; j < 4; ++j) {
            as_out[m0 + lg * 4 + j] = pa[j];
            ad_out[m0 + lg * 4 + j] = pd[j];
        }
    }
}

// ---------------- mm (layer 2) via MFMA: wave = 16-node tile, all 64 cols.
// W held in registers; A from global float4 + cvt. --------------------------
__global__ __launch_bounds__(256) void mm_mfma_kernel(
    const float* __restrict__ buf, const float* __restrict__ W,
    const float* __restrict__ avs, const float* __restrict__ avd,
    __half* __restrict__ Xh,
    float* __restrict__ as_out, float* __restrict__ ad_out) {
    int t = threadIdx.x;
    int wave = t >> 6, lane = t & 63;
    int m0 = (blockIdx.x * 4 + wave) * 16;
    if (m0 >= NN) return;
    int lr = lane & 15;
    int lg = lane >> 4;
    f16x8 bf[2][4];
#pragma unroll
    for (int kt = 0; kt < 2; ++kt)
#pragma unroll
        for (int n = 0; n < 4; ++n)
#pragma unroll
            for (int j = 0; j < 8; ++j)
                bf[kt][n][j] = (f16)W[(kt * 32 + lg * 8 + j) * 64 + n * 16 + lr];
    const float4* __restrict__ buf4 = (const float4*)buf;
    f16x8 af[2];
#pragma unroll
    for (int kt = 0; kt < 2; ++kt) {
        float4 a0 = buf4[(size_t)(m0 + lr) * 16 + kt * 8 + lg * 2];
        float4 a1 = buf4[(size_t)(m0 + lr) * 16 + kt * 8 + lg * 2 + 1];
        af[kt][0] = (f16)a0.x; af[kt][1] = (f16)a0.y;
        af[kt][2] = (f16)a0.z; af[kt][3] = (f16)a0.w;
        af[kt][4] = (f16)a1.x; af[kt][5] = (f16)a1.y;
        af[kt][6] = (f16)a1.z; af[kt][7] = (f16)a1.w;
    }
    f32x4 d[4];
#pragma unroll
    for (int n = 0; n < 4; ++n) {
        f32x4 dn = {0.f, 0.f, 0.f, 0.f};
#pragma unroll
        for (int kt = 0; kt < 2; ++kt)
            dn = __builtin_amdgcn_mfma_f32_16x16x32_f16(af[kt], bf[kt][n], dn, 0, 0, 0);
        d[n] = dn;
    }
#pragma unroll
    for (int n = 0; n < 4; ++n)
#pragma unroll
        for (int j = 0; j < 4; ++j)
            Xh[(size_t)(m0 + lg * 4 + j) * 64 + n * 16 + lr] = __float2half(d[n][j]);
    float pa[4] = {0.f, 0.f, 0.f, 0.f}, pd[4] = {0.f, 0.f, 0.f, 0.f};
#pragma unroll
    for (int n = 0; n < 4; ++n) {
        float sv = avs[n * 16 + lr], dv = avd[n * 16 + lr];
#pragma unroll
        for (int j = 0; j < 4; ++j) {
            pa[j] = fmaf(d[n][j], sv, pa[j]);
            pd[j] = fmaf(d[n][j], dv, pd[j]);
        }
    }
#pragma unroll
    for (int m = 1; m <= 8; m <<= 1) {
#pragma unroll
        for (int j = 0; j < 4; ++j) {
            pa[j] += __shfl_xor(pa[j], m, 64);
            pd[j] += __shfl_xor(pd[j], m, 64);
        }
    }
    if (lr == 0) {
#pragma unroll
        for (int j = 0; j < 4; ++j) {
            as_out[m0 + lg * 4 + j] = pa[j];
            ad_out[m0 + lg * 4 + j] = pd[j];
        }
    }
}

// ---------------- CSR build: bucket sort (LDS atomics only) ----------------
__global__ __launch_bounds__(256) void bucket_count_kernel(const int* __restrict__ dst,
                                                           int* __restrict__ cntAC) {
    __shared__ int lcnt[NBUCK];
    int c = blockIdx.x, t = threadIdx.x;
    for (int j = t; j < NBUCK; j += 256) lcnt[j] = 0;
    __syncthreads();
    int beg = c * EPB, end = beg + EPB;
    if (end > EE) end = EE;
    for (int i = beg + t; i < end; i += 256) atomicAdd(&lcnt[dst[i] >> 8], 1);
    __syncthreads();
    for (int j = t; j < NBUCK; j += 256) cntAC[j * NCHUNK + c] = lcnt[j];
}

__global__ __launch_bounds__(256) void scanA_kernel(int* __restrict__ cntAC,
                                                    int* __restrict__ bsum) {
    __shared__ int sd[256];
    int t = threadIdx.x, b = blockIdx.x;
    int base = b * 1024 + t * 4;
    int v0 = (base + 0 < SCAN_T) ? cntAC[base + 0] : 0;
    int v1 = (base + 1 < SCAN_T) ? cntAC[base + 1] : 0;
    int v2 = (base + 2 < SCAN_T) ? cntAC[base + 2] : 0;
    int v3 = (base + 3 < SCAN_T) ? cntAC[base + 3] : 0;
    int tot = v0 + v1 + v2 + v3;
    sd[t] = tot;
    __syncthreads();
    for (int off = 1; off < 256; off <<= 1) {
        int xx = (t >= off) ? sd[t - off] : 0;
        __syncthreads();
        sd[t] += xx;
        __syncthreads();
    }
    int p = sd[t] - tot;  // exclusive within block
    if (t == 255) bsum[b] = sd[255];
    if (base + 0 < SCAN_T) cntAC[base + 0] = p; p += v0;
    if (base + 1 < SCAN_T) cntAC[base + 1] = p; p += v1;
    if (base + 2 < SCAN_T) cntAC[base + 2] = p; p += v2;
    if (base + 3 < SCAN_T) cntAC[base + 3] = p;
}

__global__ __launch_bounds__(256) void scanB_kernel(int* __restrict__ bsum, int nb) {
    __shared__ int sd[256];
    int t = threadIdx.x;
    int v = (t < nb) ? bsum[t] : 0;
    sd[t] = v;
    __syncthreads();
    for (int off = 1; off < 256; off <<= 1) {
        int xx = (t >= off) ? sd[t - off] : 0;
        __syncthreads();
        sd[t] += xx;
        __syncthreads();
    }
    if (t < nb) bsum[t] = sd[t] - v;  // exclusive
}

__global__ __launch_bounds__(256) void scanC_kernel(int* __restrict__ cntAC,
                                                    const int* __restrict__ bsum,
                                                    int* __restrict__ row_off) {
    int idx = blockIdx.x * 256 + threadIdx.x;
    if (idx < SCAN_T) cntAC[idx] += bsum[idx >> 10];
    if (idx == 0) row_off[NN] = EE;
}

__global__ __launch_bounds__(256) void bucket_scatter_kernel(
    const int* __restrict__ src, const int* __restrict__ dst,
    const int* __restrict__ cntAC, int* __restrict__ eed) {
    __shared__ int lcur[NBUCK];
    int c = blockIdx.x, t = threadIdx.x;
    for (int j = t; j < NBUCK; j += 256) lcur[j] = cntAC[j * NCHUNK + c];
    __syncthreads();
    int beg = c * EPB, end = beg + EPB;
    if (end > EE) end = EE;
    for (int i = beg + t; i < end; i += 256) {
        int d = dst[i];
        int s = src[i];
        int pos = atomicAdd(&lcur[d >> 8], 1);
        eed[pos] = (s << 8) | (d & 255);
    }
}

__global__ __launch_bounds__(1024) void csr_fine_kernel(
    const int* __restrict__ eed, const int* __restrict__ cntAC,
    int* __restrict__ row_off, int* __restrict__ csr_src) {
    int b = blockIdx.x, t = threadIdx.x;
    int bb = cntAC[b * NCHUNK];
    int be = (b + 1 < NBUCK) ? cntAC[(b + 1) * NCHUNK] : EE;
    __shared__ int lcnt[256], lscan[256], lcur[256];
    __shared__ int stage[FCAP];
    if (t < 256) lcnt[t] = 0;
    __syncthreads();
    for (int i = bb + t; i < be; i += 1024) {
        int w = eed[i];
        int off = i - bb;
        if (off < FCAP) stage[off] = w;
        atomicAdd(&lcnt[w & 255], 1);
    }
    __syncthreads();
    if (t < 256) lscan[t] = lcnt[t];
    __syncthreads();
    for (int off = 1; off < 256; off <<= 1) {
        int xx = 0;
        if (t < 256 && t >= off) xx = lscan[t - off];
        __syncthreads();
        if (t < 256) lscan[t] += xx;
        __syncthreads();
    }
    if (t < 256) {
        int excl = lscan[t] - lcnt[t];
        lcur[t] = excl;
        int node = (b << 8) + t;
        if (node < NN) row_off[node] = bb + excl;
    }
    __syncthreads();
    for (int i = bb + t; i < be; i += 1024) {
        int off = i - bb;
        int w = (off < FCAP) ? stage[off] : eed[i];
        int pos = bb + atomicAdd(&lcur[w & 255], 1);
        csr_src[pos] = w >> 8;
    }
}

// ---------------- GAT: wave per dst node, 8 edges/iter, 8-lane groups each
// covering 8 cols via one fp16x8 (uint4) gather. fp32 accumulate. Explicit
// 1-stage pipeline (depth-2 on indices, depth-1 on data) — load-bearing:
// hipcc does NOT hoist gathers across iterations (r12 regression 60->68us).
// unroll 2 lets copy-prop delete the rotation movs (same pipeline depth).
// Guarded index loads (r15 showed unguarded slack loads cost FETCH+VGPR). ---
__global__ __launch_bounds__(256) void gat_kernel(
    const __half* __restrict__ Xh,  // hw fp16 [N][64]
    const float* __restrict__ asn, const float* __restrict__ adn,
    const int* __restrict__ row_off, const int* __restrict__ csr_src,
    const float* __restrict__ bias, float* __restrict__ Y,
    const float* __restrict__ gate_w, const float* __restrict__ gate_b,
    float* __restrict__ gatebuf) {
    int t = threadIdx.x;
    int wave = t >> 6, lane = t & 63;
    int v = blockIdx.x * 4 + wave;
    if (v >= NN) return;
    int grp = lane >> 3, sl = lane & 7;   // 8 groups x 8 lanes
    const uint4* __restrict__ X8 = (const uint4*)Xh;  // 8 halves per uint4
    float adv = adn[v];
    float es = asn[v] + adv;
    es = (es >= 0.f) ? es : 0.2f * es;
    float exs = __expf(es);
    float acc[8];
#pragma unroll
    for (int j = 0; j < 8; ++j) acc[j] = 0.f;
    float den = 0.f;
    if (grp == 0) {  // self loop owned by group 0
        uint4 xw = X8[v * 8 + sl];
        const __half2* hp = (const __half2*)&xw;
#pragma unroll
        for (int j = 0; j < 4; ++j) {
            float2 f = __half22float2(hp[j]);
            acc[2 * j] = exs * f.x;
            acc[2 * j + 1] = exs * f.y;
        }
        den = exs;
    }
    int beg = row_off[v], end = row_off[v + 1];
    // pipeline prologue
    int eA = beg + grp, eB = beg + 8 + grp;
    bool vA = eA < end, vB = eB < end;
    int sA = vA ? csr_src[eA] : v;
    int sB = vB ? csr_src[eB] : v;
    float asvA = asn[sA];
    uint4 xA = X8[sA * 8 + sl];
#pragma unroll 2
    for (int i = beg; i < end; i += 8) {
        // prefetch: index for i+16, data for i+8
        int eC = i + 16 + grp;
        bool vC = eC < end;
        int sC = vC ? csr_src[eC] : v;
        float asvB = asn[sB];
        uint4 xB = X8[sB * 8 + sl];
        // compute on A (landed a full iteration ago)
        float ee = asvA + adv;
        ee = (ee >= 0.f) ? ee : 0.2f * ee;
        float ex = vA ? __expf(ee) : 0.f;
        const __half2* hp = (const __half2*)&xA;
#pragma unroll
        for (int j = 0; j < 4; ++j) {
            float2 f = __half22float2(hp[j]);
            acc[2 * j] = fmaf(ex, f.x, acc[2 * j]);
            acc[2 * j + 1] = fmaf(ex, f.y, acc[2 * j + 1]);
        }
        den += ex;
        // shift
        vA = vB; vB = vC;
        sB = sC;
        asvA = asvB;
        xA = xB;
    }
    // reduce across the 8 lane groups (lanes {sl, sl+8, ..., sl+56})
#pragma unroll
    for (int m = 8; m <= 32; m <<= 1) {
#pragma unroll
        for (int j = 0; j < 8; ++j) acc[j] += __shfl_xor(acc[j], m, 64);
        den += __shfl_xor(den, m, 64);
    }
    float inv = 1.f / (den + 1e-16f);
    float o[8];
#pragma unroll
    for (int j = 0; j < 8; ++j)
        o[j] = fmaxf(acc[j] * inv + bias[sl * 8 + j], 0.f);
    if (grp == 0) {
        float4 o0 = make_float4(o[0], o[1], o[2], o[3]);
        float4 o1 = make_float4(o[4], o[5], o[6], o[7]);
        ((float4*)Y)[v * 16 + sl * 2] = o0;
        ((float4*)Y)[v * 16 + sl * 2 + 1] = o1;
    }
    if (gatebuf) {  // fused pool gate (layer 2 only)
        float p = 0.f;
#pragma unroll
        for (int j = 0; j < 8; ++j) p = fmaf(o[j], gate_w[sl * 8 + j], p);
        float gate = wave_sum(p) * 0.125f + gate_b[0];  // each col counted 8x
        if (lane == 0) gatebuf[v] = gate;
    }
}

// ---------------- pool: contiguous strip per wave, register accumulation ----
#define POOL_NPW 32  // nodes per wave
__global__ __launch_bounds__(256) void pool_kernel(
    const float* __restrict__ Hf, const float* __restrict__ gatebuf,
    const int* __restrict__ batch,
    float* __restrict__ acc, float* __restrict__ den) {
    int t = threadIdx.x, wave = t >> 6, lane = t & 63;
    int v0 = (blockIdx.x * 4 + wave) * POOL_NPW;
    if (v0 >= NN) return;
    int vend = v0 + POOL_NPW;
    if (vend > NN) vend = NN;
    int gcur = batch[v0];
    float accr = 0.f, denr = 0.f;
    for (int v = v0; v < vend; ++v) {
        int g = batch[v];
        if (g != gcur) {
            atomicAdd(&acc[gcur * 64 + lane], accr);
            if (lane == 0) atomicAdd(&den[gcur], denr);
            accr = 0.f; denr = 0.f; gcur = g;
        }
        float ex = __expf(gatebuf[v]);
        accr = fmaf(ex, Hf[(size_t)v * 64 + lane], accr);
        denr += ex;
    }
    atomicAdd(&acc[gcur * 64 + lane], accr);
    if (lane == 0) atomicAdd(&den[gcur], denr);
}

// ---------------- pool finalize + LSTM (h0=c0=0) + MLP head ----------------
__global__ __launch_bounds__(256) void head_kernel(
    const float* __restrict__ acc, const float* __restrict__ den,
    const float* __restrict__ w_ih,
    const float* __restrict__ b_ih, const float* __restrict__ b_hh,
    const float* __restrict__ q_w1, const float* __restrict__ q_b1,
    const float* __restrict__ q_w2, const float* __restrict__ q_b2,
    float* __restrict__ out) {
    int g = blockIdx.x, t = threadIdx.x;
    __shared__ float sp[64];
    __shared__ float sg[512];
    __shared__ float sh1[128];
    __shared__ float ss1[64];
    if (t < 64) sp[t] = acc[g * 64 + t] / (den[g] + 1e-16f);
    __syncthreads();
    for (int r = t; r < 512; r += 256) {
        const float* wr = w_ih + (size_t)r * 64;
        float a = b_ih[r] + b_hh[r];
#pragma unroll
        for (int k = 0; k < 64; ++k) a += sp[k] * wr[k];
        sg[r] = a;
    }
    __syncthreads();
    if (t < 128) {
        float ig = sg[t], gg = sg[256 + t], og = sg[384 + t];
        float c1 = sigmoidf(ig) * tanhf(gg);  // sigmoid(f)*c0 == 0
        float h1 = sigmoidf(og) * tanhf(c1);
        sh1[t] = h1;
        out[640 + g * 128 + t] = h1;
        out[640 + 8192 + g * 128 + t] = c1;
    }
    __syncthreads();
    if (t < 64) {
        float a = q_b1[t];
#pragma unroll
        for (int k = 0; k < 128; ++k) a += sh1[k] * q_w1[k * 64 + t];
        ss1[t] = fmaxf(a, 0.f);
    }
    __syncthreads();
    if (t < 10) {
        float a = q_b2[t];
#pragma unroll
        for (int k = 0; k < 64; ++k) a += ss1[k] * q_w2[k * 10 + t];
        out[g * 10 + t] = a;
    }
}

// ---------------- launcher ----------------
extern "C" void kernel_launch(void* const* d_in, const int* in_sizes, int n_in,
                              void* d_out, int out_size, void* d_ws, size_t ws_size,
                              hipStream_t stream) {
    const float* x = (const float*)d_in[0];
    const int* edge_index = (const int*)d_in[1];
    const int* batch = (const int*)d_in[2];
    const float* enc_w = (const float*)d_in[3];
    const float* enc_b = (const float*)d_in[4];
    const float* ln_g = (const float*)d_in[5];
    const float* ln_b = (const float*)d_in[6];
    const float* w1 = (const float*)d_in[7];
    const float* a1s = (const float*)d_in[8];
    const float* a1d = (const float*)d_in[9];
    const float* b1 = (const float*)d_in[10];
    const float* w2 = (const float*)d_in[11];
    const float* a2s = (const float*)d_in[12];
    const float* a2d = (const float*)d_in[13];
    const float* b2 = (const float*)d_in[14];
    const float* gate_w = (const float*)d_in[15];
    const float* gate_b = (const float*)d_in[16];
    const float* w_ih = (const float*)d_in[17];
    // d_in[18] = w_hh unused (h0 = 0)
    const float* b_ih = (const float*)d_in[19];
    const float* b_hh = (const float*)d_in[20];
    const float* q_w1 = (const float*)d_in[21];
    const float* q_b1 = (const float*)d_in[22];
    const float* q_w2 = (const float*)d_in[23];
    const float* q_b2 = (const float*)d_in[24];
    float* out = (float*)d_out;

    const int* e_src = edge_index;
    const int* e_dst = edge_index + EE;

    // workspace carve-up
    char* ws = (char*)d_ws;
    size_t off = 0;
    auto alloc = [&](size_t bytes) {
        size_t r = off;
        off = (off + bytes + 255) & ~(size_t)255;
        return r;
    };
    float* bufA = (float*)(ws + alloc((size_t)NN * 64 * 4));
    float* bufB = (float*)(ws + alloc((size_t)NN * 64 * 4));
    __half* Xh = (__half*)(ws + alloc((size_t)NN * 64 * 2));
    float* as_n = (float*)(ws + alloc((size_t)NN * 4));
    float* ad_n = (float*)(ws + alloc((size_t)NN * 4));
    float* gatebuf = (float*)(ws + alloc((size_t)NN * 4));
    int* row_off = (int*)(ws + alloc((size_t)(NN + 1) * 4));
    int* csr_src = (int*)(ws + alloc((size_t)EE * 4));
    int* cntAC = (int*)(ws + alloc((size_t)SCAN_T * 4));
    int* bsum = (int*)(ws + alloc((size_t)SCAN_NB * 4));
    float* pacc = (float*)(ws + alloc((size_t)GG * 64 * 4));
    float* pden = (float*)(ws + alloc((size_t)GG * 4));
    // packed edge array aliases bufB (dead before gat layer 1 writes bufB)
    int* eed = (int*)bufB;
    (void)ws_size;

    const int nodeBlocks = (NN + 3) / 4;  // wave per node
    const int mfmaBlocks = (NN / 16 + 3) / 4;  // 1563: wave per 16-node tile
    const int poolBlocks = (NN + 4 * POOL_NPW - 1) / (4 * POOL_NPW);
    const int scanCBlocks = (SCAN_T + 255) / 256;

    // CSR by dst via bucket sort (LDS atomics only; reused by both GAT layers)
    bucket_count_kernel<<<NCHUNK, 256, 0, stream>>>(e_dst, cntAC);
    scanA_kernel<<<SCAN_NB, 256, 0, stream>>>(cntAC, bsum);
    scanB_kernel<<<1, 256, 0, stream>>>(bsum, SCAN_NB);
    scanC_kernel<<<scanCBlocks, 256, 0, stream>>>(cntAC, bsum, row_off);
    bucket_scatter_kernel<<<NCHUNK, 256, 0, stream>>>(e_src, e_dst, cntAC, eed);
    csr_fine_kernel<<<NBUCK, 1024, 0, stream>>>(eed, cntAC, row_off, csr_src);

    // GAT layer 1: fused enc+MFMA mm -> fp16 Xh -> gat -> bufB(h1)
    encmm_mfma_kernel<<<mfmaBlocks, 256, 0, stream>>>(x, enc_w, enc_b, ln_g,
                                                      ln_b, w1, a1s, a1d, Xh,
                                                      as_n, ad_n);
    gat_kernel<<<nodeBlocks, 256, 0, stream>>>(Xh, as_n, ad_n, row_off, csr_src,
                                               b1, bufB, nullptr, nullptr, nullptr);

    // GAT layer 2: bufB -> MFMA mm -> fp16 Xh -> gat -> bufA(h2), fused gate
    mm_mfma_kernel<<<mfmaBlocks, 256, 0, stream>>>(bufB, w2, a2s, a2d, Xh,
                                                   as_n, ad_n);
    gat_kernel<<<nodeBlocks, 256, 0, stream>>>(Xh, as_n, ad_n, row_off, csr_src,
                                               b2, bufA, gate_w, gate_b, gatebuf);

    // pool: register-accumulated partial sums, flush-on-graph-change atomics
    hipMemsetAsync(pacc, 0, (size_t)(GG * 64 + GG) * 4 + 256, stream);
    pool_kernel<<<poolBlocks, 256, 0, stream>>>(bufA, gatebuf, batch, pacc, pden);

    // LSTM + MLP head (pool finalize fused)
    head_kernel<<<GG, 256, 0, stream>>>(pacc, pden, w_ih, b_ih, b_hh,
                                        q_w1, q_b1, q_w2, q_b2, out);
}

// Round 19
// 219.938 us; speedup vs baseline: 1.1903x; 1.0056x over previous
//
#include <hip/hip_runtime.h>
#include <hip/hip_fp16.h>
#include <math.h>

#define NN 100000
#define EE 1600000
#define GG 64
#define HH 64
#define LHH 128
#define AA 10

#define NBUCK 391            // ceil(NN/256): 256 dst nodes per bucket
#define EPB 8192             // edges per chunk
#define NCHUNK 196           // ceil(EE/EPB)
#define SCAN_T (NBUCK * NCHUNK)               // 76636
#define SCAN_NB ((SCAN_T + 1023) / 1024)      // 75
#define FCAP 8192            // LDS staging capacity in csr_fine (max bucket ~4500)

typedef _Float16 f16;
typedef f16 f16x8 __attribute__((ext_vector_type(8)));
typedef float f32x4 __attribute__((ext_vector_type(4)));

// ---------------- helpers ----------------
__device__ __forceinline__ float wave_sum(float v) {
#pragma unroll
    for (int m = 32; m >= 1; m >>= 1) v += __shfl_xor(v, m, 64);
    return v;
}
__device__ __forceinline__ float sigmoidf(float x) { return 1.f / (1.f + expf(-x)); }

// ---------------- fused encoder + mm1 via MFMA: wave = 16-node tile.
// Encoder (LN) per node into private LDS region (no barrier: same-wave
// write->read), then A from LDS, W1 in registers, 8 x mfma_16x16x32_f16.
// D layout (m89): col=lane&15, row=(lane>>4)*4+reg. ------------------------
__global__ __launch_bounds__(256) void encmm_mfma_kernel(
    const float* __restrict__ x, const float* __restrict__ enc_w,
    const float* __restrict__ enc_b, const float* __restrict__ ln_g,
    const float* __restrict__ ln_b,
    const float* __restrict__ W, const float* __restrict__ avs,
    const float* __restrict__ avd, __half* __restrict__ Xh,
    float* __restrict__ as_out, float* __restrict__ ad_out) {
    __shared__ float srow[4][16][68];  // per-wave region, +4 pad
    __shared__ float sw[5 * 64];
    int t = threadIdx.x;
    for (int i = t; i < 320; i += 256) sw[i] = enc_w[i];
    __syncthreads();
    int wave = t >> 6, lane = t & 63;
    int m0 = (blockIdx.x * 4 + wave) * 16;
    if (m0 >= NN) return;  // NN % 16 == 0: full tiles
    float eb = enc_b[lane], lgm = ln_g[lane], lbb = ln_b[lane];
    // encoder: 16 nodes per wave, lane = column
#pragma unroll 4
    for (int p = 0; p < 16; ++p) {
        int v = m0 + p;
        float a = eb;
#pragma unroll
        for (int k = 0; k < 5; ++k) a += x[v * 5 + k] * sw[k * 64 + lane];
        a = fmaxf(a, 0.f);
        float mu = wave_sum(a) * (1.f / 64.f);
        float d = a - mu;
        float var = wave_sum(d * d) * (1.f / 64.f);
        float r = 1.f / sqrtf(var + 1e-5f);
        srow[wave][p][lane] = d * r * lgm + lbb;
    }
    int lr = lane & 15;  // row (A) / col (B,D)
    int lg = lane >> 4;  // k lane-group
    // B fragments: bf[kt][n][j] = W[kt*32 + lg*8 + j][n*16 + lr]
    f16x8 bf[2][4];
#pragma unroll
    for (int kt = 0; kt < 2; ++kt)
#pragma unroll
        for (int n = 0; n < 4; ++n)
#pragma unroll
            for (int j = 0; j < 8; ++j)
                bf[kt][n][j] = (f16)W[(kt * 32 + lg * 8 + j) * 64 + n * 16 + lr];
    // A fragments from LDS: af[kt][j] = h[m0+lr][kt*32 + lg*8 + j]
    f16x8 af[2];
#pragma unroll
    for (int kt = 0; kt < 2; ++kt)
#pragma unroll
        for (int j = 0; j < 8; ++j)
            af[kt][j] = (f16)srow[wave][lr][kt * 32 + lg * 8 + j];
    // D = A*W, accumulate across kt
    f32x4 d[4];
#pragma unroll
    for (int n = 0; n < 4; ++n) {
        f32x4 dn = {0.f, 0.f, 0.f, 0.f};
#pragma unroll
        for (int kt = 0; kt < 2; ++kt)
            dn = __builtin_amdgcn_mfma_f32_16x16x32_f16(af[kt], bf[kt][n], dn, 0, 0, 0);
        d[n] = dn;
    }
    // store Xh fp16: lane holds d[n][j] = hw[m0 + lg*4 + j][n*16 + lr]
#pragma unroll
    for (int n = 0; n < 4; ++n)
#pragma unroll
        for (int j = 0; j < 4; ++j)
            Xh[(size_t)(m0 + lg * 4 + j) * 64 + n * 16 + lr] = __float2half(d[n][j]);
    // as/ad: per-row dot with avs/avd, reduce across the 16 col-lanes
    float pa[4] = {0.f, 0.f, 0.f, 0.f}, pd[4] = {0.f, 0.f, 0.f, 0.f};
#pragma unroll
    for (int n = 0; n < 4; ++n) {
        float sv = avs[n * 16 + lr], dv = avd[n * 16 + lr];
#pragma unroll
        for (int j = 0; j < 4; ++j) {
            pa[j] = fmaf(d[n][j], sv, pa[j]);
            pd[j] = fmaf(d[n][j], dv, pd[j]);
        }
    }
#pragma unroll
    for (int m = 1; m <= 8; m <<= 1) {
#pragma unroll
        for (int j = 0; j < 4; ++j) {
            pa[j] += __shfl_xor(pa[j], m, 64);
            pd[j] += __shfl_xor(pd[j], m, 64);
        }
    }
    if (lr == 0) {
#pragma unroll
        for (int j = 0; j < 4; ++j) {
            as_out[m0 + lg * 4 + j] = pa[j];
            ad_out[m0 + lg * 4 + j] = pd[j];
        }
    }
}

// ---------------- mm (layer 2) via MFMA: wave = 16-node tile, all 64 cols.
// W in registers; A is fp16 h1 rows read as raw f16x8 fragments (no cvt). ---
__global__ __launch_bounds__(256) void mm_mfma_kernel(
    const __half* __restrict__ buf, const float* __restrict__ W,
    const float* __restrict__ avs, const float* __restrict__ avd,
    __half* __restrict__ Xh,
    float* __restrict__ as_out, float* __restrict__ ad_out) {
    int t = threadIdx.x;
    int wave = t >> 6, lane = t & 63;
    int m0 = (blockIdx.x * 4 + wave) * 16;
    if (m0 >= NN) return;
    int lr = lane & 15;
    int lg = lane >> 4;
    f16x8 bf[2][4];
#pragma unroll
    for (int kt = 0; kt < 2; ++kt)
#pragma unroll
        for (int n = 0; n < 4; ++n)
#pragma unroll
            for (int j = 0; j < 8; ++j)
                bf[kt][n][j] = (f16)W[(kt * 32 + lg * 8 + j) * 64 + n * 16 + lr];
    const f16x8* __restrict__ buf8 = (const f16x8*)buf;  // 8 halves per elem
    f16x8 af[2];
#pragma unroll
    for (int kt = 0; kt < 2; ++kt)
        af[kt] = buf8[(size_t)(m0 + lr) * 8 + kt * 4 + lg];
    f32x4 d[4];
#pragma unroll
    for (int n = 0; n < 4; ++n) {
        f32x4 dn = {0.f, 0.f, 0.f, 0.f};
#pragma unroll
        for (int kt = 0; kt < 2; ++kt)
            dn = __builtin_amdgcn_mfma_f32_16x16x32_f16(af[kt], bf[kt][n], dn, 0, 0, 0);
        d[n] = dn;
    }
#pragma unroll
    for (int n = 0; n < 4; ++n)
#pragma unroll
        for (int j = 0; j < 4; ++j)
            Xh[(size_t)(m0 + lg * 4 + j) * 64 + n * 16 + lr] = __float2half(d[n][j]);
    float pa[4] = {0.f, 0.f, 0.f, 0.f}, pd[4] = {0.f, 0.f, 0.f, 0.f};
#pragma unroll
    for (int n = 0; n < 4; ++n) {
        float sv = avs[n * 16 + lr], dv = avd[n * 16 + lr];
#pragma unroll
        for (int j = 0; j < 4; ++j) {
            pa[j] = fmaf(d[n][j], sv, pa[j]);
            pd[j] = fmaf(d[n][j], dv, pd[j]);
        }
    }
#pragma unroll
    for (int m = 1; m <= 8; m <<= 1) {
#pragma unroll
        for (int j = 0; j < 4; ++j) {
            pa[j] += __shfl_xor(pa[j], m, 64);
            pd[j] += __shfl_xor(pd[j], m, 64);
        }
    }
    if (lr == 0) {
#pragma unroll
        for (int j = 0; j < 4; ++j) {
            as_out[m0 + lg * 4 + j] = pa[j];
            ad_out[m0 + lg * 4 + j] = pd[j];
        }
    }
}

// ---------------- CSR build: bucket sort (LDS atomics only) ----------------
__global__ __launch_bounds__(256) void bucket_count_kernel(const int* __restrict__ dst,
                                                           int* __restrict__ cntAC) {
    __shared__ int lcnt[NBUCK];
    int c = blockIdx.x, t = threadIdx.x;
    for (int j = t; j < NBUCK; j += 256) lcnt[j] = 0;
    __syncthreads();
    int beg = c * EPB, end = beg + EPB;
    if (end > EE) end = EE;
    for (int i = beg + t; i < end; i += 256) atomicAdd(&lcnt[dst[i] >> 8], 1);
    __syncthreads();
    for (int j = t; j < NBUCK; j += 256) cntAC[j * NCHUNK + c] = lcnt[j];
}

__global__ __launch_bounds__(256) void scanA_kernel(int* __restrict__ cntAC,
                                                    int* __restrict__ bsum) {
    __shared__ int sd[256];
    int t = threadIdx.x, b = blockIdx.x;
    int base = b * 1024 + t * 4;
    int v0 = (base + 0 < SCAN_T) ? cntAC[base + 0] : 0;
    int v1 = (base + 1 < SCAN_T) ? cntAC[base + 1] : 0;
    int v2 = (base + 2 < SCAN_T) ? cntAC[base + 2] : 0;
    int v3 = (base + 3 < SCAN_T) ? cntAC[base + 3] : 0;
    int tot = v0 + v1 + v2 + v3;
    sd[t] = tot;
    __syncthreads();
    for (int off = 1; off < 256; off <<= 1) {
        int xx = (t >= off) ? sd[t - off] : 0;
        __syncthreads();
        sd[t] += xx;
        __syncthreads();
    }
    int p = sd[t] - tot;  // exclusive within block
    if (t == 255) bsum[b] = sd[255];
    if (base + 0 < SCAN_T) cntAC[base + 0] = p; p += v0;
    if (base + 1 < SCAN_T) cntAC[base + 1] = p; p += v1;
    if (base + 2 < SCAN_T) cntAC[base + 2] = p; p += v2;
    if (base + 3 < SCAN_T) cntAC[base + 3] = p;
}

__global__ __launch_bounds__(256) void scanB_kernel(int* __restrict__ bsum, int nb) {
    __shared__ int sd[256];
    int t = threadIdx.x;
    int v = (t < nb) ? bsum[t] : 0;
    sd[t] = v;
    __syncthreads();
    for (int off = 1; off < 256; off <<= 1) {
        int xx = (t >= off) ? sd[t - off] : 0;
        __syncthreads();
        sd[t] += xx;
        __syncthreads();
    }
    if (t < nb) bsum[t] = sd[t] - v;  // exclusive
}

__global__ __launch_bounds__(256) void scanC_kernel(int* __restrict__ cntAC,
                                                    const int* __restrict__ bsum,
                                                    int* __restrict__ row_off) {
    int idx = blockIdx.x * 256 + threadIdx.x;
    if (idx < SCAN_T) cntAC[idx] += bsum[idx >> 10];
    if (idx == 0) row_off[NN] = EE;
}

__global__ __launch_bounds__(256) void bucket_scatter_kernel(
    const int* __restrict__ src, const int* __restrict__ dst,
    const int* __restrict__ cntAC, int* __restrict__ eed) {
    __shared__ int lcur[NBUCK];
    int c = blockIdx.x, t = threadIdx.x;
    for (int j = t; j < NBUCK; j += 256) lcur[j] = cntAC[j * NCHUNK + c];
    __syncthreads();
    int beg = c * EPB, end = beg + EPB;
    if (end > EE) end = EE;
    for (int i = beg + t; i < end; i += 256) {
        int d = dst[i];
        int s = src[i];
        int pos = atomicAdd(&lcur[d >> 8], 1);
        eed[pos] = (s << 8) | (d & 255);
    }
}

__global__ __launch_bounds__(1024) void csr_fine_kernel(
    const int* __restrict__ eed, const int* __restrict__ cntAC,
    int* __restrict__ row_off, int* __restrict__ csr_src) {
    int b = blockIdx.x, t = threadIdx.x;
    int bb = cntAC[b * NCHUNK];
    int be = (b + 1 < NBUCK) ? cntAC[(b + 1) * NCHUNK] : EE;
    __shared__ int lcnt[256], lscan[256], lcur[256];
    __shared__ int stage[FCAP];
    if (t < 256) lcnt[t] = 0;
    __syncthreads();
    for (int i = bb + t; i < be; i += 1024) {
        int w = eed[i];
        int off = i - bb;
        if (off < FCAP) stage[off] = w;
        atomicAdd(&lcnt[w & 255], 1);
    }
    __syncthreads();
    if (t < 256) lscan[t] = lcnt[t];
    __syncthreads();
    for (int off = 1; off < 256; off <<= 1) {
        int xx = 0;
        if (t < 256 && t >= off) xx = lscan[t - off];
        __syncthreads();
        if (t < 256) lscan[t] += xx;
        __syncthreads();
    }
    if (t < 256) {
        int excl = lscan[t] - lcnt[t];
        lcur[t] = excl;
        int node = (b << 8) + t;
        if (node < NN) row_off[node] = bb + excl;
    }
    __syncthreads();
    for (int i = bb + t; i < be; i += 1024) {
        int off = i - bb;
        int w = (off < FCAP) ? stage[off] : eed[i];
        int pos = bb + atomicAdd(&lcur[w & 255], 1);
        csr_src[pos] = w >> 8;
    }
}

// ---------------- GAT: wave per dst node, 8 edges/iter, 8-lane groups each
// covering 8 cols via one fp16x8 (uint4) gather. fp32 accumulate. Explicit
// 1-stage pipeline (depth-2 on indices, depth-1 on data) — load-bearing:
// hipcc does NOT hoist gathers across iterations (r12 regression 60->68us).
// unroll 2 lets copy-prop delete the rotation movs. Guarded index loads
// (r15: unguarded slack loads cost FETCH+VGPR). Y output stored fp16. ------
__global__ __launch_bounds__(256) void gat_kernel(
    const __half* __restrict__ Xh,  // hw fp16 [N][64]
    const float* __restrict__ asn, const float* __restrict__ adn,
    const int* __restrict__ row_off, const int* __restrict__ csr_src,
    const float* __restrict__ bias, __half* __restrict__ Y,
    const float* __restrict__ gate_w, const float* __restrict__ gate_b,
    float* __restrict__ gatebuf) {
    int t = threadIdx.x;
    int wave = t >> 6, lane = t & 63;
    int v = blockIdx.x * 4 + wave;
    if (v >= NN) return;
    int grp = lane >> 3, sl = lane & 7;   // 8 groups x 8 lanes
    const uint4* __restrict__ X8 = (const uint4*)Xh;  // 8 halves per uint4
    float adv = adn[v];
    float es = asn[v] + adv;
    es = (es >= 0.f) ? es : 0.2f * es;
    float exs = __expf(es);
    float acc[8];
#pragma unroll
    for (int j = 0; j < 8; ++j) acc[j] = 0.f;
    float den = 0.f;
    if (grp == 0) {  // self loop owned by group 0
        uint4 xw = X8[v * 8 + sl];
        const __half2* hp = (const __half2*)&xw;
#pragma unroll
        for (int j = 0; j < 4; ++j) {
            float2 f = __half22float2(hp[j]);
            acc[2 * j] = exs * f.x;
            acc[2 * j + 1] = exs * f.y;
        }
        den = exs;
    }
    int beg = row_off[v], end = row_off[v + 1];
    // pipeline prologue
    int eA = beg + grp, eB = beg + 8 + grp;
    bool vA = eA < end, vB = eB < end;
    int sA = vA ? csr_src[eA] : v;
    int sB = vB ? csr_src[eB] : v;
    float asvA = asn[sA];
    uint4 xA = X8[sA * 8 + sl];
#pragma unroll 2
    for (int i = beg; i < end; i += 8) {
        // prefetch: index for i+16, data for i+8
        int eC = i + 16 + grp;
        bool vC = eC < end;
        int sC = vC ? csr_src[eC] : v;
        float asvB = asn[sB];
        uint4 xB = X8[sB * 8 + sl];
        // compute on A (landed a full iteration ago)
        float ee = asvA + adv;
        ee = (ee >= 0.f) ? ee : 0.2f * ee;
        float ex = vA ? __expf(ee) : 0.f;
        const __half2* hp = (const __half2*)&xA;
#pragma unroll
        for (int j = 0; j < 4; ++j) {
            float2 f = __half22float2(hp[j]);
            acc[2 * j] = fmaf(ex, f.x, acc[2 * j]);
            acc[2 * j + 1] = fmaf(ex, f.y, acc[2 * j + 1]);
        }
        den += ex;
        // shift
        vA = vB; vB = vC;
        sB = sC;
        asvA = asvB;
        xA = xB;
    }
    // reduce across the 8 lane groups (lanes {sl, sl+8, ..., sl+56})
#pragma unroll
    for (int m = 8; m <= 32; m <<= 1) {
#pragma unroll
        for (int j = 0; j < 8; ++j) acc[j] += __shfl_xor(acc[j], m, 64);
        den += __shfl_xor(den, m, 64);
    }
    float inv = 1.f / (den + 1e-16f);
    float o[8];
#pragma unroll
    for (int j = 0; j < 8; ++j)
        o[j] = fmaxf(acc[j] * inv + bias[sl * 8 + j], 0.f);
    if (grp == 0) {  // pack 8 cols as fp16 (one uint4 per lane)
        __half2 p0 = __floats2half2_rn(o[0], o[1]);
        __half2 p1 = __floats2half2_rn(o[2], o[3]);
        __half2 p2 = __floats2half2_rn(o[4], o[5]);
        __half2 p3 = __floats2half2_rn(o[6], o[7]);
        uint4 pk;
        pk.x = *(unsigned int*)&p0;
        pk.y = *(unsigned int*)&p1;
        pk.z = *(unsigned int*)&p2;
        pk.w = *(unsigned int*)&p3;
        ((uint4*)Y)[v * 8 + sl] = pk;
    }
    if (gatebuf) {  // fused pool gate (layer 2 only)
        float p = 0.f;
#pragma unroll
        for (int j = 0; j < 8; ++j) p = fmaf(o[j], gate_w[sl * 8 + j], p);
        float gate = wave_sum(p) * 0.125f + gate_b[0];  // each col counted 8x
        if (lane == 0) gatebuf[v] = gate;
    }
}

// ---------------- pool: contiguous strip per wave, register accumulation ----
#define POOL_NPW 32  // nodes per wave
__global__ __launch_bounds__(256) void pool_kernel(
    const __half* __restrict__ Hf, const float* __restrict__ gatebuf,
    const int* __restrict__ batch,
    float* __restrict__ acc, float* __restrict__ den) {
    int t = threadIdx.x, wave = t >> 6, lane = t & 63;
    int v0 = (blockIdx.x * 4 + wave) * POOL_NPW;
    if (v0 >= NN) return;
    int vend = v0 + POOL_NPW;
    if (vend > NN) vend = NN;
    int gcur = batch[v0];
    float accr = 0.f, denr = 0.f;
    for (int v = v0; v < vend; ++v) {
        int g = batch[v];
        if (g != gcur) {
            atomicAdd(&acc[gcur * 64 + lane], accr);
            if (lane == 0) atomicAdd(&den[gcur], denr);
            accr = 0.f; denr = 0.f; gcur = g;
        }
        float ex = __expf(gatebuf[v]);
        accr = fmaf(ex, __half2float(Hf[(size_t)v * 64 + lane]), accr);
        denr += ex;
    }
    atomicAdd(&acc[gcur * 64 + lane], accr);
    if (lane == 0) atomicAdd(&den[gcur], denr);
}

// ---------------- pool finalize + LSTM (h0=c0=0) + MLP head ----------------
__global__ __launch_bounds__(256) void head_kernel(
    const float* __restrict__ acc, const float* __restrict__ den,
    const float* __restrict__ w_ih,
    const float* __restrict__ b_ih, const float* __restrict__ b_hh,
    const float* __restrict__ q_w1, const float* __restrict__ q_b1,
    const float* __restrict__ q_w2, const float* __restrict__ q_b2,
    float* __restrict__ out) {
    int g = blockIdx.x, t = threadIdx.x;
    __shared__ float sp[64];
    __shared__ float sg[512];
    __shared__ float sh1[128];
    __shared__ float ss1[64];
    if (t < 64) sp[t] = acc[g * 64 + t] / (den[g] + 1e-16f);
    __syncthreads();
    for (int r = t; r < 512; r += 256) {
        const float* wr = w_ih + (size_t)r * 64;
        float a = b_ih[r] + b_hh[r];
#pragma unroll
        for (int k = 0; k < 64; ++k) a += sp[k] * wr[k];
        sg[r] = a;
    }
    __syncthreads();
    if (t < 128) {
        float ig = sg[t], gg = sg[256 + t], og = sg[384 + t];
        float c1 = sigmoidf(ig) * tanhf(gg);  // sigmoid(f)*c0 == 0
        float h1 = sigmoidf(og) * tanhf(c1);
        sh1[t] = h1;
        out[640 + g * 128 + t] = h1;
        out[640 + 8192 + g * 128 + t] = c1;
    }
    __syncthreads();
    if (t < 64) {
        float a = q_b1[t];
#pragma unroll
        for (int k = 0; k < 128; ++k) a += sh1[k] * q_w1[k * 64 + t];
        ss1[t] = fmaxf(a, 0.f);
    }
    __syncthreads();
    if (t < 10) {
        float a = q_b2[t];
#pragma unroll
        for (int k = 0; k < 64; ++k) a += ss1[k] * q_w2[k * 10 + t];
        out[g * 10 + t] = a;
    }
}

// ---------------- launcher ----------------
extern "C" void kernel_launch(void* const* d_in, const int* in_sizes, int n_in,
                              void* d_out, int out_size, void* d_ws, size_t ws_size,
                              hipStream_t stream) {
    const float* x = (const float*)d_in[0];
    const int* edge_index = (const int*)d_in[1];
    const int* batch = (const int*)d_in[2];
    const float* enc_w = (const float*)d_in[3];
    const float* enc_b = (const float*)d_in[4];
    const float* ln_g = (const float*)d_in[5];
    const float* ln_b = (const float*)d_in[6];
    const float* w1 = (const float*)d_in[7];
    const float* a1s = (const float*)d_in[8];
    const float* a1d = (const float*)d_in[9];
    const float* b1 = (const float*)d_in[10];
    const float* w2 = (const float*)d_in[11];
    const float* a2s = (const float*)d_in[12];
    const float* a2d = (const float*)d_in[13];
    const float* b2 = (const float*)d_in[14];
    const float* gate_w = (const float*)d_in[15];
    const float* gate_b = (const float*)d_in[16];
    const float* w_ih = (const float*)d_in[17];
    // d_in[18] = w_hh unused (h0 = 0)
    const float* b_ih = (const float*)d_in[19];
    const float* b_hh = (const float*)d_in[20];
    const float* q_w1 = (const float*)d_in[21];
    const float* q_b1 = (const float*)d_in[22];
    const float* q_w2 = (const float*)d_in[23];
    const float* q_b2 = (const float*)d_in[24];
    float* out = (float*)d_out;

    const int* e_src = edge_index;
    const int* e_dst = edge_index + EE;

    // workspace carve-up
    char* ws = (char*)d_ws;
    size_t off = 0;
    auto alloc = [&](size_t bytes) {
        size_t r = off;
        off = (off + bytes + 255) & ~(size_t)255;
        return r;
    };
    __half* bufA = (__half*)(ws + alloc((size_t)NN * 64 * 2));  // h2 fp16
    __half* bufB = (__half*)(ws + alloc((size_t)NN * 64 * 2));  // h1 fp16
    __half* Xh = (__half*)(ws + alloc((size_t)NN * 64 * 2));
    float* as_n = (float*)(ws + alloc((size_t)NN * 4));
    float* ad_n = (float*)(ws + alloc((size_t)NN * 4));
    float* gatebuf = (float*)(ws + alloc((size_t)NN * 4));
    int* row_off = (int*)(ws + alloc((size_t)(NN + 1) * 4));
    int* csr_src = (int*)(ws + alloc((size_t)EE * 4));
    int* cntAC = (int*)(ws + alloc((size_t)SCAN_T * 4));
    int* bsum = (int*)(ws + alloc((size_t)SCAN_NB * 4));
    float* pacc = (float*)(ws + alloc((size_t)GG * 64 * 4));
    float* pden = (float*)(ws + alloc((size_t)GG * 4));
    // packed edge array aliases bufB (12.8MB >= 6.4MB needed; dead before
    // gat layer 1 writes bufB)
    int* eed = (int*)bufB;
    (void)ws_size;

    const int nodeBlocks = (NN + 3) / 4;  // wave per node
    const int mfmaBlocks = (NN / 16 + 3) / 4;  // 1563: wave per 16-node tile
    const int poolBlocks = (NN + 4 * POOL_NPW - 1) / (4 * POOL_NPW);
    const int scanCBlocks = (SCAN_T + 255) / 256;

    // CSR by dst via bucket sort (LDS atomics only; reused by both GAT layers)
    bucket_count_kernel<<<NCHUNK, 256, 0, stream>>>(e_dst, cntAC);
    scanA_kernel<<<SCAN_NB, 256, 0, stream>>>(cntAC, bsum);
    scanB_kernel<<<1, 256, 0, stream>>>(bsum, SCAN_NB);
    scanC_kernel<<<scanCBlocks, 256, 0, stream>>>(cntAC, bsum, row_off);
    bucket_scatter_kernel<<<NCHUNK, 256, 0, stream>>>(e_src, e_dst, cntAC, eed);
    csr_fine_kernel<<<NBUCK, 1024, 0, stream>>>(eed, cntAC, row_off, csr_src);

    // GAT layer 1: fused enc+MFMA mm -> fp16 Xh -> gat -> bufB(h1 fp16)
    encmm_mfma_kernel<<<mfmaBlocks, 256, 0, stream>>>(x, enc_w, enc_b, ln_g,
                                                      ln_b, w1, a1s, a1d, Xh,
                                                      as_n, ad_n);
    gat_kernel<<<nodeBlocks, 256, 0, stream>>>(Xh, as_n, ad_n, row_off, csr_src,
                                               b1, bufB, nullptr, nullptr, nullptr);

    // GAT layer 2: bufB(fp16) -> MFMA mm -> fp16 Xh -> gat -> bufA(h2 fp16)
    mm_mfma_kernel<<<mfmaBlocks, 256, 0, stream>>>(bufB, w2, a2s, a2d, Xh,
                                                   as_n, ad_n);
    gat_kernel<<<nodeBlocks, 256, 0, stream>>>(Xh, as_n, ad_n, row_off, csr_src,
                                               b2, bufA, gate_w, gate_b, gatebuf);

    // pool: register-accumulated partial sums, flush-on-graph-change atomics
    hipMemsetAsync(pacc, 0, (size_t)(GG * 64 + GG) * 4 + 256, stream);
    pool_kernel<<<poolBlocks, 256, 0, stream>>>(bufA, gatebuf, batch, pacc, pden);

    // LSTM + MLP head (pool finalize fused)
    head_kernel<<<GG, 256, 0, stream>>>(pacc, pden, w_ih, b_ih, b_hh,
                                        q_w1, q_b1, q_w2, q_b2, out);
}